// Round 12
// baseline (347.344 us; speedup 1.0000x reference)
//
#include <hip/hip_runtime.h>
#include <math.h>

#define LNUM 2
#define BBATCH 4
#define TSEQ 1000
#define CDIM 768
#define HHEADS 12
#define DKK 64
#define PPOS (2*TSEQ-1)   // 1999
#define HALFW 50
#define MROWS (BBATCH*TSEQ)     // 4000
#define MPAD 4096
#define QKVDIM (3*CDIM)         // 2304
#define NS 176                  // real key span per 64-query tile (padded to 192)
#define NSTEP (CDIM/32)         // 24 k-steps

typedef __attribute__((ext_vector_type(8))) short s16x8;
typedef __attribute__((ext_vector_type(4))) short s16x4;
typedef __attribute__((ext_vector_type(4))) float f32x4;

#define LDSOFF(p) ((unsigned)(uintptr_t)(__attribute__((address_space(3))) const void*)(p))

__device__ __forceinline__ ushort f2bf(float x) {
    unsigned u = __float_as_uint(x);
    unsigned r = u + 0x7FFFu + ((u >> 16) & 1u);
    return (ushort)(r >> 16);
}
__device__ __forceinline__ float bf2f(ushort h) {
    return __uint_as_float(((unsigned)h) << 16);
}
__device__ __forceinline__ float gelu_f(float x) {
    float u = 0.7978845608028654f * (x + 0.044715f * x * x * x);
    return 0.5f * x * (1.f + tanhf(u));
}
__device__ __forceinline__ void gload_lds16(const void* g, void* l) {
    __builtin_amdgcn_global_load_lds(
        (const __attribute__((address_space(1))) void*)g,
        (__attribute__((address_space(3))) void*)l, 16, 0, 0);
}
__device__ __forceinline__ s16x4 tr_read(unsigned addr) {
    s16x4 d;
    asm volatile("ds_read_b64_tr_b16 %0, %1" : "=v"(d) : "v"(addr));
    return d;
}
__device__ __forceinline__ s16x4 tr_read128(unsigned addr) {
    s16x4 d;
    asm volatile("ds_read_b64_tr_b16 %0, %1 offset:128" : "=v"(d) : "v"(addr));
    return d;
}
// bijective XCD-chunked swizzle (m204)
__device__ __forceinline__ int xcd_swz(int orig, int nwg) {
    const int xcd = orig & 7, ixc = orig >> 3;
    const int qq = nwg >> 3, rr = nwg & 7;
    return (xcd < rr ? xcd * (qq + 1) : rr * (qq + 1) + (xcd - rr) * qq) + ixc;
}

// ---------------- weight transpose + bf16 convert, fused with small prep ----------------
__global__ __launch_bounds__(256) void transpose_pack(
    const float* __restrict__ Wq, const float* __restrict__ Wk,
    const float* __restrict__ Wv, const float* __restrict__ Wp,
    const float* __restrict__ Wo, const float* __restrict__ W1,
    const float* __restrict__ W2,
    ushort* __restrict__ Wtqkv, ushort* __restrict__ Wtp,
    ushort* __restrict__ Wto, ushort* __restrict__ Wt1, ushort* __restrict__ Wt2,
    ushort* __restrict__ pe,
    const float* __restrict__ bq, const float* __restrict__ bk,
    const float* __restrict__ bv, float* __restrict__ bqkv) {
    const int tx = threadIdx.x, ty = threadIdx.y;       // (8, 32)
    if (blockIdx.z == 14) {
        const int linear = blockIdx.y * 24 + blockIdx.x;
        const int idx = linear * 256 + ty * 8 + tx;
        const int npair = 256 * (CDIM / 2);
        if (idx < npair) {
            int jloc = idx / (CDIM / 2);
            int m = idx - jloc * (CDIM / 2);
            int j = 896 + jloc;
            float rel = (float)(TSEQ - 1 - j);
            float div = expf(-(float)(2 * m) * (9.210340371976184f / (float)CDIM));
            float a = rel * div;
            pe[(size_t)j * CDIM + 2 * m]     = f2bf(sinf(a));
            pe[(size_t)j * CDIM + 2 * m + 1] = f2bf(cosf(a));
        }
        if (idx < LNUM * QKVDIM) {
            int l = idx / QKVDIM, c = idx - l * QKVDIM;
            float v;
            if (c < CDIM)            v = bq[l * CDIM + c];
            else if (c < 2 * CDIM)   v = bk[l * CDIM + c - CDIM];
            else                     v = bv[l * CDIM + c - 2 * CDIM];
            bqkv[idx] = v;
        }
        return;
    }
    const int l = blockIdx.z / 7, m = blockIdx.z % 7;
    const float* srcs[7] = {Wq, Wk, Wv, Wp, Wo, W1, W2};
    const float* src = srcs[m] + (size_t)l * CDIM * CDIM;
    ushort* dst;
    if (m < 3)       dst = Wtqkv + (size_t)l * QKVDIM * CDIM + (size_t)m * CDIM * CDIM;
    else if (m == 3) dst = Wtp + (size_t)l * CDIM * CDIM;
    else if (m == 4) dst = Wto + (size_t)l * CDIM * CDIM;
    else if (m == 5) dst = Wt1 + (size_t)l * CDIM * CDIM;
    else             dst = Wt2 + (size_t)l * CDIM * CDIM;
    __shared__ float tile[32][33];
    const int c0 = blockIdx.x * 32, r0 = blockIdx.y * 32;
    const float4 v = *(const float4*)&src[(size_t)(r0 + ty) * CDIM + c0 + tx * 4];
    tile[tx * 4 + 0][ty] = v.x;
    tile[tx * 4 + 1][ty] = v.y;
    tile[tx * 4 + 2][ty] = v.z;
    tile[tx * 4 + 3][ty] = v.w;
    __syncthreads();
    const float a0 = tile[ty][tx * 4 + 0], a1 = tile[ty][tx * 4 + 1];
    const float a2 = tile[ty][tx * 4 + 2], a3 = tile[ty][tx * 4 + 3];
    uint2 pk;
    pk.x = (unsigned)f2bf(a0) | ((unsigned)f2bf(a1) << 16);
    pk.y = (unsigned)f2bf(a2) | ((unsigned)f2bf(a3) << 16);
    *(uint2*)&dst[(size_t)(c0 + ty) * CDIM + r0 + tx * 4] = pk;
}

// ---------------- LayerNorm: f32 in (xscale-on-load), bf16 out; 192 thr, float4 ----------------
__global__ __launch_bounds__(192) void ln_kernel(const float* __restrict__ in,
                                                 const float* __restrict__ g,
                                                 const float* __restrict__ bta,
                                                 ushort* __restrict__ y, float xscale) {
    const int row = blockIdx.x, tid = threadIdx.x;
    float4 v = *(const float4*)&in[(size_t)row * CDIM + tid * 4];
    v.x *= xscale; v.y *= xscale; v.z *= xscale; v.w *= xscale;
    float s  = v.x + v.y + v.z + v.w;
    float ss = v.x * v.x + v.y * v.y + v.z * v.z + v.w * v.w;
#pragma unroll
    for (int off = 32; off; off >>= 1) {
        s  += __shfl_xor(s, off);
        ss += __shfl_xor(ss, off);
    }
    __shared__ float sm[3], sq[3];
    const int wid = tid >> 6, lane = tid & 63;
    if (lane == 0) { sm[wid] = s; sq[wid] = ss; }
    __syncthreads();
    const float st  = sm[0] + sm[1] + sm[2];
    const float sst = sq[0] + sq[1] + sq[2];
    const float mean = st * (1.f / CDIM);
    const float var  = sst * (1.f / CDIM) - mean * mean;
    const float rstd = rsqrtf(var + 1e-5f);
    const float4 g4 = *(const float4*)&g[tid * 4];
    const float4 b4 = *(const float4*)&bta[tid * 4];
    ushort o0 = f2bf((v.x - mean) * rstd * g4.x + b4.x);
    ushort o1 = f2bf((v.y - mean) * rstd * g4.y + b4.y);
    ushort o2 = f2bf((v.z - mean) * rstd * g4.z + b4.z);
    ushort o3 = f2bf((v.w - mean) * rstd * g4.w + b4.w);
    uint2 pk; pk.x = (unsigned)o0 | ((unsigned)o1 << 16);
    pk.y = (unsigned)o2 | ((unsigned)o3 << 16);
    *(uint2*)&y[(size_t)row * CDIM + tid * 4] = pk;
}

// ---------------- MFMA bf16 GEMM: 128x128 tile, BK=32, depth-3 counted-vmcnt pipeline ----
// 5 LDS buffers x 16 KB (80 KB -> 2 blocks/CU). Per k-step t:
//   vmcnt(12)  -> own 4 loads for step t (the oldest outstanding) have landed
//   s_barrier  -> publishes every wave's wait AND proves compute t-1 finished
//   STAGE(t+4) -> buf (t+4)%5 == buf (t-1)%5, whose readers finished at that barrier
//   compute t  -> buf t%5 (ds_read XOR-swizzled, compiler inserts lgkm waits)
// Tail uses vmcnt(8/4/0). XOR chunk swizzle: slot = c ^ ((r>>1)&3), source pre-permuted.
// EPI 0: bf16 store; 1: gelu->bf16; 2: Out(f32) = resid*rscale + acc + bias
template <int EPI>
__global__ __launch_bounds__(256, 2) void gemm128d(const ushort* __restrict__ A,
                                                   const ushort* __restrict__ Bt,
                                                   const float* __restrict__ bias,
                                                   void* Out, int M, int ldo,
                                                   const float* resid, float rscale,
                                                   size_t zsB, size_t zsO) {
    __shared__ ushort lds[5 * 8192];           // 5 x 16 KB
    const int tid = threadIdx.x;
    const int w = tid >> 6, lane = tid & 63;
    const int nwg = gridDim.x * gridDim.y;
    const int newid = xcd_swz(blockIdx.y * gridDim.x + blockIdx.x, nwg);
    const int col0 = (newid % gridDim.y) * 128;
    const int row0 = (newid / gridDim.y) * 128;
    Bt += blockIdx.z * zsB;
    if (EPI == 2) Out = (void*)((float*)Out + blockIdx.z * zsO);
    else          Out = (void*)((ushort*)Out + blockIdx.z * zsO);
    const int srow   = lane >> 2;                        // row within 16-row span
    const int schunk = (lane & 3) ^ ((lane >> 3) & 3);   // pre-swizzled source chunk
    const int wm = (w >> 1) * 64, wn = (w & 1) * 64;
    const int lr = lane & 15, q = lane >> 4;

#define STG(s)                                                                   \
    {                                                                            \
        _Pragma("unroll")                                                        \
        for (int g = 0; g < 4; ++g) {                                            \
            const int sp = w * 4 + g;                                            \
            const int r = sp * 16 + srow;                                        \
            const ushort* src = (r < 128)                                        \
                ? A  + (size_t)(row0 + r) * CDIM + (s) * 32 + schunk * 8         \
                : Bt + (size_t)(col0 + (r - 128)) * CDIM + (s) * 32 + schunk * 8;\
            gload_lds16(src, (char*)lds + ((s) % 5) * 16384 + sp * 1024);        \
        }                                                                        \
    }

    f32x4 acc[4][4] = {};
    STG(0); STG(1); STG(2); STG(3);
    for (int t = 0; t < NSTEP; ++t) {
        if (t < NSTEP - 3)       asm volatile("s_waitcnt vmcnt(12)" ::: "memory");
        else if (t == NSTEP - 3) asm volatile("s_waitcnt vmcnt(8)" ::: "memory");
        else if (t == NSTEP - 2) asm volatile("s_waitcnt vmcnt(4)" ::: "memory");
        else                     asm volatile("s_waitcnt vmcnt(0)" ::: "memory");
        __builtin_amdgcn_sched_barrier(0);
        __builtin_amdgcn_s_barrier();
        __builtin_amdgcn_sched_barrier(0);
        if (t + 4 < NSTEP) STG(t + 4);
        const int base = (t % 5) * 8192;
        s16x8 af[4], bfr[4];
#pragma unroll
        for (int i = 0; i < 4; ++i) {
            const int r = wm + i * 16 + lr;
            af[i] = *(const s16x8*)&lds[base + r * 32 + ((q ^ ((r >> 1) & 3)) << 3)];
        }
#pragma unroll
        for (int j = 0; j < 4; ++j) {
            const int r = 128 + wn + j * 16 + lr;
            bfr[j] = *(const s16x8*)&lds[base + r * 32 + ((q ^ ((r >> 1) & 3)) << 3)];
        }
#pragma unroll
        for (int i = 0; i < 4; ++i)
#pragma unroll
            for (int j = 0; j < 4; ++j)
                acc[i][j] = __builtin_amdgcn_mfma_f32_16x16x32_bf16(af[i], bfr[j], acc[i][j], 0, 0, 0);
    }
#undef STG

    const int crow0 = row0 + (w >> 1) * 64;
    const int ccol0 = col0 + (w & 1) * 64;
    const int lrr = (lane >> 4) * 4;
    const int lc = lane & 15;
#pragma unroll
    for (int j = 0; j < 4; ++j) {
        const int col = ccol0 + j * 16 + lc;
        const float bv = bias ? bias[col] : 0.f;
#pragma unroll
        for (int i = 0; i < 4; ++i) {
#pragma unroll
            for (int r = 0; r < 4; ++r) {
                const int row = crow0 + i * 16 + lrr + r;
                if (row >= M) continue;
                const float v = acc[i][j][r] + bv;
                if (EPI == 0)
                    ((ushort*)Out)[(size_t)row * ldo + col] = f2bf(v);
                else if (EPI == 1)
                    ((ushort*)Out)[(size_t)row * ldo + col] = f2bf(gelu_f(v));
                else {
                    float* p = (float*)Out + (size_t)row * ldo + col;
                    *p = resid[(size_t)row * ldo + col] * rscale + v;
                }
            }
        }
    }
}

// ---------------- MFMA banded rel-pos attention (round-11 structure, verified) ----------------
__global__ __launch_bounds__(256, 3) void attn_mfma(
    const ushort* __restrict__ qkv, const ushort* __restrict__ pb,
    const float* __restrict__ pos_u, const float* __restrict__ pos_v,
    ushort* __restrict__ o) {
    __shared__ __align__(16) char smem[51200];
    ushort* Kl   = (ushort*)smem;               // [176][64] swizzled
    ushort* Pl   = (ushort*)smem;               // phase2 [64][200]
    ushort* Vsub = (ushort*)(smem + 25600);     // [2][192][16]
    ushort* Bd   = (ushort*)(smem + 37888);     // [4][16][104]

    const int tid = threadIdx.x;
    const int w = tid >> 6, lane = tid & 63;
    const int t0 = blockIdx.x * 64;
    const int h = blockIdx.y, b = blockIdx.z;
    const int m0 = w * 16;
    const int lr = lane & 15, lk = (lane >> 4) * 8, q = lane >> 4;

    auto vsrc = [&](int sp) -> const ushort* {
        const int ob = sp * 1024 + lane * 16;
        const int d0c = ob / 6144;
        const int rem = ob - d0c * 6144;
        const int j = rem >> 5;
        const int halfo = (rem & 31) >> 4;
        int t = t0 - HALFW + j; t = t < 0 ? 0 : (t < TSEQ ? t : TSEQ - 1);
        return qkv + (size_t)(b * TSEQ + t) * QKVDIM + 2 * CDIM + h * DKK
               + (d0c & 1) * 16 + halfo * 8;
    };

    int tq = t0 + m0 + lr; tq = tq < TSEQ ? tq : TSEQ - 1;
    const ushort* qp = qkv + (size_t)(b * TSEQ + tq) * QKVDIM + h * DKK;
    s16x8 qr0 = *(const s16x8*)(qp + lk);
    s16x8 qr1 = *(const s16x8*)(qp + 32 + lk);
    const float* puB = pos_u + h * DKK;
    const float* pvB = pos_v + h * DKK;
    float puA[16], pvA[16];
    *(float4*)&puA[0]  = *(const float4*)(puB + lk);
    *(float4*)&puA[4]  = *(const float4*)(puB + lk + 4);
    *(float4*)&puA[8]  = *(const float4*)(puB + 32 + lk);
    *(float4*)&puA[12] = *(const float4*)(puB + 32 + lk + 4);
    *(float4*)&pvA[0]  = *(const float4*)(pvB + lk);
    *(float4*)&pvA[4]  = *(const float4*)(pvB + lk + 4);
    *(float4*)&pvA[8]  = *(const float4*)(pvB + 32 + lk);
    *(float4*)&pvA[12] = *(const float4*)(pvB + 32 + lk + 4);

#pragma unroll
    for (int g = 0; g < 3; ++g) {
        const int sp = w * 3 + g;
        gload_lds16(vsrc(sp), (char*)Vsub + sp * 1024);
    }
    {
        const int srow8 = lane >> 3;
        const int schunk = (lane & 7) ^ srow8;
#pragma unroll
        for (int g = 0; g < 6; ++g) {
            const int sp = w * 6 + g;
            if (sp < 22) {
                const int r = sp * 8 + srow8;
                int kb = t0 - HALFW + r; kb = kb < 0 ? 0 : (kb < TSEQ ? kb : TSEQ - 1);
                const ushort* src = qkv + (size_t)(b * TSEQ + kb) * QKVDIM + CDIM
                                    + h * DKK + schunk * 8;
                gload_lds16(src, (char*)Kl + sp * 1024);
            }
        }
    }

    s16x8 qu0, qu1, qv0, qv1;
#pragma unroll
    for (int e = 0; e < 8; ++e) {
        const float q0 = bf2f((ushort)qr0[e]), q1 = bf2f((ushort)qr1[e]);
        qu0[e] = (short)f2bf(q0 + puA[e]);
        qu1[e] = (short)f2bf(q1 + puA[8 + e]);
        qv0[e] = (short)f2bf(q0 + pvA[e]);
        qv1[e] = (short)f2bf(q1 + pvA[8 + e]);
    }

    const ushort* pbh = pb + (size_t)949 * CDIM + h * DKK;
    s16x8 pfr[7][2];
#pragma unroll
    for (int uf = 0; uf < 7; ++uf) {
        pfr[uf][0] = *(const s16x8*)&pbh[(size_t)(uf * 16 + lr) * CDIM + lk];
        pfr[uf][1] = *(const s16x8*)&pbh[(size_t)(uf * 16 + lr) * CDIM + 32 + lk];
    }
    __syncthreads();

    const f32x4 zero = {0.f, 0.f, 0.f, 0.f};
    f32x4 acS[11], acB[7];
    __builtin_amdgcn_s_setprio(1);
#pragma unroll
    for (int uf = 0; uf < 7; ++uf) {
        acB[uf] = __builtin_amdgcn_mfma_f32_16x16x32_bf16(qv0, pfr[uf][0], zero, 0, 0, 0);
        acB[uf] = __builtin_amdgcn_mfma_f32_16x16x32_bf16(qv1, pfr[uf][1], acB[uf], 0, 0, 0);
    }
#pragma unroll
    for (int jf = 0; jf < 11; ++jf) {
        const int rr = jf * 16 + lr;
        const int sw = rr & 7;
        s16x8 k0 = *(const s16x8*)&Kl[rr * 64 + (((q)     ^ sw) << 3)];
        s16x8 k1 = *(const s16x8*)&Kl[rr * 64 + (((q | 4) ^ sw) << 3)];
        acS[jf] = __builtin_amdgcn_mfma_f32_16x16x32_bf16(qu0, k0, zero, 0, 0, 0);
        acS[jf] = __builtin_amdgcn_mfma_f32_16x16x32_bf16(qu1, k1, acS[jf], 0, 0, 0);
    }
    __builtin_amdgcn_s_setprio(0);

    ushort* bdw = Bd + w * 16 * 104;
#pragma unroll
    for (int uf = 0; uf < 7; ++uf)
#pragma unroll
        for (int r = 0; r < 4; ++r)
            bdw[((lane >> 4) * 4 + r) * 104 + uf * 16 + lr] = f2bf(acB[uf][r]);
    float mx[4] = {-1e30f, -1e30f, -1e30f, -1e30f};
#pragma unroll
    for (int jf = 0; jf < 11; ++jf)
#pragma unroll
        for (int r = 0; r < 4; ++r) {
            const int tl = (lane >> 4) * 4 + r;
            const int tloc = m0 + tl;
            const int j = jf * 16 + lr;
            const int u = j - tloc;
            const int s = t0 - HALFW + j;
            const bool valid = (u >= 0) & (u <= 2 * HALFW) & (s >= 0) & (s < TSEQ)
                               & (t0 + tloc < TSEQ);
            float sc = -1e30f;
            if (valid) sc = (acS[jf][r] + bf2f(bdw[tl * 104 + u])) * 0.125f;
            acS[jf][r] = sc;
            mx[r] = fmaxf(mx[r], sc);
        }
#pragma unroll
    for (int r = 0; r < 4; ++r)
#pragma unroll
        for (int off = 8; off; off >>= 1)
            mx[r] = fmaxf(mx[r], __shfl_xor(mx[r], off));
    float sm[4] = {0.f, 0.f, 0.f, 0.f};
#pragma unroll
    for (int jf = 0; jf < 11; ++jf)
#pragma unroll
        for (int r = 0; r < 4; ++r) {
            float e = __expf(acS[jf][r] - mx[r]);
            acS[jf][r] = e;
            sm[r] += e;
        }
#pragma unroll
    for (int r = 0; r < 4; ++r) {
#pragma unroll
        for (int off = 8; off; off >>= 1) sm[r] += __shfl_xor(sm[r], off);
        sm[r] = 1.f / sm[r];
    }
    __syncthreads();

    s16x8 vr0 = *vsrc(12 + w * 3 + 0);
    s16x8 vr1 = *vsrc(12 + w * 3 + 1);
    s16x8 vr2 = *vsrc(12 + w * 3 + 2);

#pragma unroll
    for (int jf = 0; jf < 11; ++jf)
#pragma unroll
        for (int r = 0; r < 4; ++r)
            Pl[(m0 + (lane >> 4) * 4 + r) * 200 + jf * 16 + lr] = f2bf(acS[jf][r]);
#pragma unroll
    for (int r = 0; r < 4; ++r)
        Pl[(m0 + (lane >> 4) * 4 + r) * 200 + 176 + lr] = 0;

    s16x8 pa[6];
#pragma unroll
    for (int ks = 0; ks < 6; ++ks)
        pa[ks] = *(const s16x8*)&Pl[(m0 + lr) * 200 + ks * 32 + lk];

    const unsigned vbase = LDSOFF(Vsub);
#pragma unroll
    for (int nf = 0; nf < 2; ++nf) {
        const unsigned abase = vbase + (nf & 1) * 6144 + ((lane >> 4) << 8) + ((lane & 15) << 1);
        s16x4 lo[6], hi[6];
#pragma unroll
        for (int ks = 0; ks < 6; ++ks) {
            lo[ks] = tr_read(abase + ks * 1024);
            hi[ks] = tr_read128(abase + ks * 1024);
        }
        asm volatile("s_waitcnt lgkmcnt(0)" ::: "memory");
        __builtin_amdgcn_sched_barrier(0);
        f32x4 acO = {};
        __builtin_amdgcn_s_setprio(1);
#pragma unroll
        for (int ks = 0; ks < 6; ++ks) {
            s16x8 vb = __builtin_shufflevector(lo[ks], hi[ks], 0, 1, 2, 3, 4, 5, 6, 7);
            acO = __builtin_amdgcn_mfma_f32_16x16x32_bf16(pa[ks], vb, acO, 0, 0, 0);
        }
        __builtin_amdgcn_s_setprio(0);
#pragma unroll
        for (int r = 0; r < 4; ++r) {
            const int t = t0 + m0 + (lane >> 4) * 4 + r;
            if (t < TSEQ)
                o[(size_t)(b * TSEQ + t) * CDIM + h * DKK + nf * 16 + lr] =
                    f2bf(acO[r] * sm[r]);
        }
    }
    __syncthreads();

    *(s16x8*)((char*)Vsub + (w * 3 + 0) * 1024 + lane * 16) = vr0;
    *(s16x8*)((char*)Vsub + (w * 3 + 1) * 1024 + lane * 16) = vr1;
    *(s16x8*)((char*)Vsub + (w * 3 + 2) * 1024 + lane * 16) = vr2;
    __syncthreads();

#pragma unroll
    for (int nf = 2; nf < 4; ++nf) {
        const unsigned abase = vbase + (nf & 1) * 6144 + ((lane >> 4) << 8) + ((lane & 15) << 1);
        s16x4 lo[6], hi[6];
#pragma unroll
        for (int ks = 0; ks < 6; ++ks) {
            lo[ks] = tr_read(abase + ks * 1024);
            hi[ks] = tr_read128(abase + ks * 1024);
        }
        asm volatile("s_waitcnt lgkmcnt(0)" ::: "memory");
        __builtin_amdgcn_sched_barrier(0);
        f32x4 acO = {};
        __builtin_amdgcn_s_setprio(1);
#pragma unroll
        for (int ks = 0; ks < 6; ++ks) {
            s16x8 vb = __builtin_shufflevector(lo[ks], hi[ks], 0, 1, 2, 3, 4, 5, 6, 7);
            acO = __builtin_amdgcn_mfma_f32_16x16x32_bf16(pa[ks], vb, acO, 0, 0, 0);
        }
        __builtin_amdgcn_s_setprio(0);
#pragma unroll
        for (int r = 0; r < 4; ++r) {
            const int t = t0 + m0 + (lane >> 4) * 4 + r;
            if (t < TSEQ)
                o[(size_t)(b * TSEQ + t) * CDIM + h * DKK + nf * 16 + lr] =
                    f2bf(acO[r] * sm[r]);
        }
    }
}

// ---------------- launch ----------------
extern "C" void kernel_launch(void* const* d_in, const int* in_sizes, int n_in,
                              void* d_out, int out_size, void* d_ws, size_t ws_size,
                              hipStream_t stream) {
    const float* x     = (const float*)d_in[0];
    const float* Wq    = (const float*)d_in[1];
    const float* bq    = (const float*)d_in[2];
    const float* Wk    = (const float*)d_in[3];
    const float* bk    = (const float*)d_in[4];
    const float* Wv    = (const float*)d_in[5];
    const float* bv    = (const float*)d_in[6];
    const float* Wo    = (const float*)d_in[7];
    const float* bo    = (const float*)d_in[8];
    const float* Wp    = (const float*)d_in[9];
    const float* pos_u = (const float*)d_in[10];
    const float* pos_v = (const float*)d_in[11];
    const float* ln1g  = (const float*)d_in[12];
    const float* ln1b  = (const float*)d_in[13];
    const float* ln2g  = (const float*)d_in[14];
    const float* ln2b  = (const float*)d_in[15];
    const float* W1    = (const float*)d_in[16];
    const float* b1    = (const float*)d_in[17];
    const float* W2    = (const float*)d_in[18];
    const float* b2    = (const float*)d_in[19];

    float* h = (float*)d_out;
    const float XS = 27.712812921102035f;   // sqrt(768)

    char* p = (char*)d_ws;
    ushort* Wtqkv = (ushort*)p;               p += (size_t)LNUM * QKVDIM * CDIM * 2;
    ushort* Wtp   = (ushort*)p;               p += (size_t)LNUM * CDIM * CDIM * 2;
    ushort* Wto   = (ushort*)p;               p += (size_t)LNUM * CDIM * CDIM * 2;
    ushort* Wt1   = (ushort*)p;               p += (size_t)LNUM * CDIM * CDIM * 2;
    ushort* Wt2   = (ushort*)p;               p += (size_t)LNUM * CDIM * CDIM * 2;
    float*  bqkv  = (float*)p;                p += (size_t)LNUM * QKVDIM * 4;
    ushort* pe    = (ushort*)p;               p += (size_t)2048 * CDIM * 2;
    ushort* pb    = (ushort*)p;               p += (size_t)LNUM * 2048 * CDIM * 2;
    ushort* y     = (ushort*)p;               p += (size_t)MPAD * CDIM * 2;
    ushort* qkv   = (ushort*)p;               p += (size_t)MPAD * QKVDIM * 2;
    ushort* o     = (ushort*)p;               p += (size_t)MPAD * CDIM * 2;
    ushort* hid   = (ushort*)p;               p += (size_t)MPAD * CDIM * 2;

    transpose_pack<<<dim3(24, 24, 15), dim3(8, 32), 0, stream>>>(
        Wq, Wk, Wv, Wp, Wo, W1, W2, Wtqkv, Wtp, Wto, Wt1, Wt2,
        pe, bq, bk, bv, bqkv);

    const dim3 gQKV(32, QKVDIM / 128);       // (32, 18)
    const dim3 gC(32, CDIM / 128);           // (32, 6)
    const dim3 gP(2, CDIM / 128, LNUM);      // M=256 rel-pos rows, both layers
    const dim3 gA(16, HHEADS, BBATCH);

    gemm128d<0><<<gP, 256, 0, stream>>>(pe + (size_t)896 * CDIM, Wtp, nullptr,
                                        pb + (size_t)896 * CDIM, 256, CDIM,
                                        nullptr, 0.f,
                                        (size_t)CDIM * CDIM, (size_t)2048 * CDIM);

    for (int l = 0; l < LNUM; ++l) {
        const size_t wo = (size_t)l * CDIM * CDIM;
        const float* res1 = (l == 0) ? x : h;
        const float rs1   = (l == 0) ? XS : 1.f;
        ln_kernel<<<MROWS, 192, 0, stream>>>(res1, ln1g + l * CDIM, ln1b + l * CDIM, y, rs1);
        gemm128d<0><<<gQKV, 256, 0, stream>>>(y, Wtqkv + (size_t)l * QKVDIM * CDIM,
                                              bqkv + l * QKVDIM, qkv, MROWS, QKVDIM,
                                              nullptr, 0.f, 0, 0);
        attn_mfma<<<gA, 256, 0, stream>>>(
            qkv, pb + (size_t)l * 2048 * CDIM,
            pos_u + l * HHEADS * DKK, pos_v + l * HHEADS * DKK, o);
        gemm128d<2><<<gC, 256, 0, stream>>>(o, Wto + wo, bo + l * CDIM, h, MROWS, CDIM,
                                            res1, rs1, 0, 0);
        ln_kernel<<<MROWS, 192, 0, stream>>>(h, ln2g + l * CDIM, ln2b + l * CDIM, y, 1.f);
        gemm128d<1><<<gC, 256, 0, stream>>>(y, Wt1 + wo, b1 + l * CDIM, hid, MROWS, CDIM,
                                            nullptr, 0.f, 0, 0);
        gemm128d<2><<<gC, 256, 0, stream>>>(hid, Wt2 + wo, b2 + l * CDIM, h, MROWS, CDIM,
                                            h, 1.f, 0, 0);
    }
}

// Round 13
// 246.792 us; speedup vs baseline: 1.4074x; 1.4074x over previous
//
#include <hip/hip_runtime.h>
#include <math.h>

#define LNUM 2
#define BBATCH 4
#define TSEQ 1000
#define CDIM 768
#define HHEADS 12
#define DKK 64
#define PPOS (2*TSEQ-1)   // 1999
#define HALFW 50
#define MROWS (BBATCH*TSEQ)     // 4000
#define MPAD 4096
#define QKVDIM (3*CDIM)         // 2304
#define NS 176                  // real key span per 64-query tile (padded to 192)

typedef __attribute__((ext_vector_type(8))) short s16x8;
typedef __attribute__((ext_vector_type(4))) short s16x4;
typedef __attribute__((ext_vector_type(4))) float f32x4;

#define LDSOFF(p) ((unsigned)(uintptr_t)(__attribute__((address_space(3))) const void*)(p))

__device__ __forceinline__ ushort f2bf(float x) {
    unsigned u = __float_as_uint(x);
    unsigned r = u + 0x7FFFu + ((u >> 16) & 1u);
    return (ushort)(r >> 16);
}
__device__ __forceinline__ float bf2f(ushort h) {
    return __uint_as_float(((unsigned)h) << 16);
}
__device__ __forceinline__ float gelu_f(float x) {
    float u = 0.7978845608028654f * (x + 0.044715f * x * x * x);
    return 0.5f * x * (1.f + tanhf(u));
}
__device__ __forceinline__ void gload_lds16(const void* g, void* l) {
    __builtin_amdgcn_global_load_lds(
        (const __attribute__((address_space(1))) void*)g,
        (__attribute__((address_space(3))) void*)l, 16, 0, 0);
}
__device__ __forceinline__ s16x4 tr_read(unsigned addr) {
    s16x4 d;
    asm volatile("ds_read_b64_tr_b16 %0, %1" : "=v"(d) : "v"(addr));
    return d;
}
__device__ __forceinline__ s16x4 tr_read128(unsigned addr) {
    s16x4 d;
    asm volatile("ds_read_b64_tr_b16 %0, %1 offset:128" : "=v"(d) : "v"(addr));
    return d;
}
// bijective XCD-chunked swizzle (m204): contiguous tile chunk per XCD
__device__ __forceinline__ int xcd_swz(int orig, int nwg) {
    const int xcd = orig & 7, ixc = orig >> 3;
    const int qq = nwg >> 3, rr = nwg & 7;
    return (xcd < rr ? xcd * (qq + 1) : rr * (qq + 1) + (xcd - rr) * qq) + ixc;
}

// ---------------- weight transpose + bf16 convert, fused with small prep ----------------
// z 0..13: weight slice l*7+m; z==14: pos-enc rows [896,1152) + qkv bias pack.
__global__ __launch_bounds__(256) void transpose_pack(
    const float* __restrict__ Wq, const float* __restrict__ Wk,
    const float* __restrict__ Wv, const float* __restrict__ Wp,
    const float* __restrict__ Wo, const float* __restrict__ W1,
    const float* __restrict__ W2,
    ushort* __restrict__ Wtqkv, ushort* __restrict__ Wtp,
    ushort* __restrict__ Wto, ushort* __restrict__ Wt1, ushort* __restrict__ Wt2,
    ushort* __restrict__ pe,
    const float* __restrict__ bq, const float* __restrict__ bk,
    const float* __restrict__ bv, float* __restrict__ bqkv) {
    const int tx = threadIdx.x, ty = threadIdx.y;       // (8, 32)
    if (blockIdx.z == 14) {
        const int linear = blockIdx.y * 24 + blockIdx.x;
        const int idx = linear * 256 + ty * 8 + tx;
        const int npair = 256 * (CDIM / 2);
        if (idx < npair) {
            int jloc = idx / (CDIM / 2);
            int m = idx - jloc * (CDIM / 2);
            int j = 896 + jloc;
            float rel = (float)(TSEQ - 1 - j);
            float div = expf(-(float)(2 * m) * (9.210340371976184f / (float)CDIM));
            float a = rel * div;
            pe[(size_t)j * CDIM + 2 * m]     = f2bf(sinf(a));
            pe[(size_t)j * CDIM + 2 * m + 1] = f2bf(cosf(a));
        }
        if (idx < LNUM * QKVDIM) {
            int l = idx / QKVDIM, c = idx - l * QKVDIM;
            float v;
            if (c < CDIM)            v = bq[l * CDIM + c];
            else if (c < 2 * CDIM)   v = bk[l * CDIM + c - CDIM];
            else                     v = bv[l * CDIM + c - 2 * CDIM];
            bqkv[idx] = v;
        }
        return;
    }
    const int l = blockIdx.z / 7, m = blockIdx.z % 7;
    const float* srcs[7] = {Wq, Wk, Wv, Wp, Wo, W1, W2};
    const float* src = srcs[m] + (size_t)l * CDIM * CDIM;
    ushort* dst;
    if (m < 3)       dst = Wtqkv + (size_t)l * QKVDIM * CDIM + (size_t)m * CDIM * CDIM;
    else if (m == 3) dst = Wtp + (size_t)l * CDIM * CDIM;
    else if (m == 4) dst = Wto + (size_t)l * CDIM * CDIM;
    else if (m == 5) dst = Wt1 + (size_t)l * CDIM * CDIM;
    else             dst = Wt2 + (size_t)l * CDIM * CDIM;
    __shared__ float tile[32][33];
    const int c0 = blockIdx.x * 32, r0 = blockIdx.y * 32;
    const float4 v = *(const float4*)&src[(size_t)(r0 + ty) * CDIM + c0 + tx * 4];
    tile[tx * 4 + 0][ty] = v.x;
    tile[tx * 4 + 1][ty] = v.y;
    tile[tx * 4 + 2][ty] = v.z;
    tile[tx * 4 + 3][ty] = v.w;
    __syncthreads();
    const float a0 = tile[ty][tx * 4 + 0], a1 = tile[ty][tx * 4 + 1];
    const float a2 = tile[ty][tx * 4 + 2], a3 = tile[ty][tx * 4 + 3];
    uint2 pk;
    pk.x = (unsigned)f2bf(a0) | ((unsigned)f2bf(a1) << 16);
    pk.y = (unsigned)f2bf(a2) | ((unsigned)f2bf(a3) << 16);
    *(uint2*)&dst[(size_t)(c0 + ty) * CDIM + r0 + tx * 4] = pk;
}

// ---------------- LayerNorm: f32 in (xscale-on-load), bf16 out; 192 thr, float4 ----------------
__global__ __launch_bounds__(192) void ln_kernel(const float* __restrict__ in,
                                                 const float* __restrict__ g,
                                                 const float* __restrict__ bta,
                                                 ushort* __restrict__ y, float xscale) {
    const int row = blockIdx.x, tid = threadIdx.x;
    float4 v = *(const float4*)&in[(size_t)row * CDIM + tid * 4];
    v.x *= xscale; v.y *= xscale; v.z *= xscale; v.w *= xscale;
    float s  = v.x + v.y + v.z + v.w;
    float ss = v.x * v.x + v.y * v.y + v.z * v.z + v.w * v.w;
#pragma unroll
    for (int off = 32; off; off >>= 1) {
        s  += __shfl_xor(s, off);
        ss += __shfl_xor(ss, off);
    }
    __shared__ float sm[3], sq[3];
    const int wid = tid >> 6, lane = tid & 63;
    if (lane == 0) { sm[wid] = s; sq[wid] = ss; }
    __syncthreads();
    const float st  = sm[0] + sm[1] + sm[2];
    const float sst = sq[0] + sq[1] + sq[2];
    const float mean = st * (1.f / CDIM);
    const float var  = sst * (1.f / CDIM) - mean * mean;
    const float rstd = rsqrtf(var + 1e-5f);
    const float4 g4 = *(const float4*)&g[tid * 4];
    const float4 b4 = *(const float4*)&bta[tid * 4];
    ushort o0 = f2bf((v.x - mean) * rstd * g4.x + b4.x);
    ushort o1 = f2bf((v.y - mean) * rstd * g4.y + b4.y);
    ushort o2 = f2bf((v.z - mean) * rstd * g4.z + b4.z);
    ushort o3 = f2bf((v.w - mean) * rstd * g4.w + b4.w);
    uint2 pk; pk.x = (unsigned)o0 | ((unsigned)o1 << 16);
    pk.y = (unsigned)o2 | ((unsigned)o3 << 16);
    *(uint2*)&y[(size_t)row * CDIM + tid * 4] = pk;
}

// ---------------- MFMA bf16 GEMM: 64x128 tile, BK=64, dbuf, XCD-swizzled ----------------
template <int EPI>
__global__ __launch_bounds__(256, 3) void gemm64(const ushort* __restrict__ A,
                                                 const ushort* __restrict__ Bt,
                                                 const float* __restrict__ bias,
                                                 void* Out, int M, int ldo,
                                                 const float* resid, float rscale,
                                                 size_t zsB, size_t zsO) {
    __shared__ ushort lds[24576];              // 2 x 24 KB
    const int tid = threadIdx.x;
    const int w = tid >> 6, lane = tid & 63;
    const int nwg = gridDim.x * gridDim.y;
    const int newid = xcd_swz(blockIdx.y * gridDim.x + blockIdx.x, nwg);
    const int col0 = (newid % gridDim.y) * 128;     // col-fastest: XCD keeps B panels hot
    const int row0 = (newid / gridDim.y) * 64;
    const size_t zb = blockIdx.z;
    Bt += zb * zsB;
    if (EPI == 2) Out = (void*)((float*)Out + zb * zsO);
    else          Out = (void*)((ushort*)Out + zb * zsO);

    const int srow8  = lane >> 3;
    const int schunk = (lane & 7) ^ srow8;

#define STAGE64(buf, k0)                                                        \
    {                                                                           \
        _Pragma("unroll")                                                       \
        for (int g = 0; g < 6; ++g) {                                           \
            const int grp = w * 6 + g;                                          \
            const int r = grp * 8 + srow8;                                      \
            const ushort* src = (grp < 8)                                       \
                ? A  + (size_t)(row0 + r) * CDIM + (k0) + schunk * 8            \
                : Bt + (size_t)(col0 + (r - 64)) * CDIM + (k0) + schunk * 8;    \
            gload_lds16(src, (char*)lds + (buf) * 24576 + grp * 1024);          \
        }                                                                       \
    }

    const int wm = (w >> 1) * 32, wn = (w & 1) * 64;
    const int lr = lane & 15, q = lane >> 4;
    f32x4 acc[2][4] = {};

    STAGE64(0, 0);
    __syncthreads();
    int cur = 0;
    for (int k0 = 0; k0 < CDIM; k0 += 64) {
        if (k0 + 64 < CDIM) STAGE64(cur ^ 1, k0 + 64);
        const int base = cur * 12288;
#pragma unroll
        for (int kk = 0; kk < 2; ++kk) {
            s16x8 af[2], bfr[4];
#pragma unroll
            for (int i = 0; i < 2; ++i) {
                const int r = wm + i * 16 + lr;
                af[i] = *(const s16x8*)&lds[base + r * 64 + ((((kk << 2) | q) ^ (r & 7)) << 3)];
            }
#pragma unroll
            for (int j = 0; j < 4; ++j) {
                const int r = 64 + wn + j * 16 + lr;
                bfr[j] = *(const s16x8*)&lds[base + r * 64 + ((((kk << 2) | q) ^ (r & 7)) << 3)];
            }
#pragma unroll
            for (int i = 0; i < 2; ++i)
#pragma unroll
                for (int j = 0; j < 4; ++j)
                    acc[i][j] = __builtin_amdgcn_mfma_f32_16x16x32_bf16(af[i], bfr[j], acc[i][j], 0, 0, 0);
        }
        __syncthreads();
        cur ^= 1;
    }
#undef STAGE64

    const int lrr = (lane >> 4) * 4;
    const int lc = lane & 15;
#pragma unroll
    for (int j = 0; j < 4; ++j) {
        const int col = col0 + wn + j * 16 + lc;
        const float bv = bias ? bias[col] : 0.f;
#pragma unroll
        for (int i = 0; i < 2; ++i) {
#pragma unroll
            for (int r = 0; r < 4; ++r) {
                const int row = row0 + wm + i * 16 + lrr + r;
                if (row >= M) continue;
                const float v = acc[i][j][r] + bv;
                if (EPI == 0)
                    ((ushort*)Out)[(size_t)row * ldo + col] = f2bf(v);
                else if (EPI == 1)
                    ((ushort*)Out)[(size_t)row * ldo + col] = f2bf(gelu_f(v));
                else {
                    float* p = (float*)Out + (size_t)row * ldo + col;
                    *p = resid[(size_t)row * ldo + col] * rscale + v;
                }
            }
        }
    }
}

// ---------------- MFMA bf16 GEMM: 128x128 tile, BK=32, dbuf, XCD-swizzled ----------------
template <int EPI>
__global__ __launch_bounds__(256, 3) void gemm128(const ushort* __restrict__ A,
                                                  const ushort* __restrict__ Bt,
                                                  const float* __restrict__ bias,
                                                  void* Out, int M, int ldo) {
    __shared__ ushort lds[16384];              // 2 x 16 KB
    const int tid = threadIdx.x;
    const int w = tid >> 6, lane = tid & 63;
    const int nwg = gridDim.x * gridDim.y;
    const int newid = xcd_swz(blockIdx.y * gridDim.x + blockIdx.x, nwg);
    const int col0 = (newid % gridDim.y) * 128;
    const int row0 = (newid / gridDim.y) * 128;
    const int srow   = lane >> 2;
    const int schunk = (lane & 3) ^ ((lane >> 3) & 3);
    const int wm = (w >> 1) * 64, wn = (w & 1) * 64;
    const int lr = lane & 15, q = lane >> 4;

#define STAGE128(buf, k0)                                                       \
    {                                                                           \
        _Pragma("unroll")                                                       \
        for (int g = 0; g < 4; ++g) {                                           \
            const int sp = w * 4 + g;                                           \
            const int r = sp * 16 + srow;                                       \
            const ushort* src = (r < 128)                                       \
                ? A  + (size_t)(row0 + r) * CDIM + (k0) + schunk * 8            \
                : Bt + (size_t)(col0 + (r - 128)) * CDIM + (k0) + schunk * 8;   \
            gload_lds16(src, (char*)lds + (buf) * 16384 + sp * 1024);           \
        }                                                                       \
    }

    f32x4 acc[4][4] = {};
    STAGE128(0, 0);
    __syncthreads();
    int cur = 0;
    for (int k0 = 0; k0 < CDIM; k0 += 32) {
        if (k0 + 32 < CDIM) STAGE128(cur ^ 1, k0 + 32);
        const int base = cur * 8192;
        s16x8 af[4], bfr[4];
#pragma unroll
        for (int i = 0; i < 4; ++i) {
            const int r = wm + i * 16 + lr;
            af[i] = *(const s16x8*)&lds[base + r * 32 + ((q ^ ((r >> 1) & 3)) << 3)];
        }
#pragma unroll
        for (int j = 0; j < 4; ++j) {
            const int r = 128 + wn + j * 16 + lr;
            bfr[j] = *(const s16x8*)&lds[base + r * 32 + ((q ^ ((r >> 1) & 3)) << 3)];
        }
#pragma unroll
        for (int i = 0; i < 4; ++i)
#pragma unroll
            for (int j = 0; j < 4; ++j)
                acc[i][j] = __builtin_amdgcn_mfma_f32_16x16x32_bf16(af[i], bfr[j], acc[i][j], 0, 0, 0);
        __syncthreads();
        cur ^= 1;
    }
#undef STAGE128

    const int crow0 = row0 + (w >> 1) * 64;
    const int ccol0 = col0 + (w & 1) * 64;
    const int lrr = (lane >> 4) * 4;
    const int lc = lane & 15;
#pragma unroll
    for (int j = 0; j < 4; ++j) {
        const int col = ccol0 + j * 16 + lc;
        const float bv = bias ? bias[col] : 0.f;
#pragma unroll
        for (int i = 0; i < 4; ++i) {
#pragma unroll
            for (int r = 0; r < 4; ++r) {
                const int row = crow0 + i * 16 + lrr + r;
                if (row >= M) continue;
                const float v = acc[i][j][r] + bv;
                if (EPI == 0)
                    ((ushort*)Out)[(size_t)row * ldo + col] = f2bf(v);
                else if (EPI == 1)
                    ((ushort*)Out)[(size_t)row * ldo + col] = f2bf(gelu_f(v));
            }
        }
    }
}

// ---------------- MFMA banded rel-pos attention (round-8 structure, reg-pressure reorder) ----------------
__global__ __launch_bounds__(256, 3) void attn_mfma(
    const ushort* __restrict__ qkv, const ushort* __restrict__ pb,
    const float* __restrict__ pos_u, const float* __restrict__ pos_v,
    ushort* __restrict__ o) {
    __shared__ __align__(16) char smem[51200];
    ushort* Kl   = (ushort*)smem;               // [176][64] swizzled
    ushort* Pl   = (ushort*)smem;               // phase2 [64][200]
    ushort* Vsub = (ushort*)(smem + 25600);     // [2][192][16]
    ushort* Bd   = (ushort*)(smem + 37888);     // [4][16][104]

    const int tid = threadIdx.x;
    const int w = tid >> 6, lane = tid & 63;
    const int t0 = blockIdx.x * 64;
    const int h = blockIdx.y, b = blockIdx.z;
    const int m0 = w * 16;
    const int lr = lane & 15, lk = (lane >> 4) * 8, q = lane >> 4;

    auto vsrc = [&](int sp) -> const ushort* {
        const int ob = sp * 1024 + lane * 16;
        const int d0c = ob / 6144;
        const int rem = ob - d0c * 6144;
        const int j = rem >> 5;
        const int halfo = (rem & 31) >> 4;
        int t = t0 - HALFW + j; t = t < 0 ? 0 : (t < TSEQ ? t : TSEQ - 1);
        return qkv + (size_t)(b * TSEQ + t) * QKVDIM + 2 * CDIM + h * DKK
               + (d0c & 1) * 16 + halfo * 8;
    };

    // ---- Q + pos loads (oldest VMEM) ----
    int tq = t0 + m0 + lr; tq = tq < TSEQ ? tq : TSEQ - 1;
    const ushort* qp = qkv + (size_t)(b * TSEQ + tq) * QKVDIM + h * DKK;
    s16x8 qr0 = *(const s16x8*)(qp + lk);
    s16x8 qr1 = *(const s16x8*)(qp + 32 + lk);
    const float* puB = pos_u + h * DKK;
    const float* pvB = pos_v + h * DKK;
    float puA[16], pvA[16];
    *(float4*)&puA[0]  = *(const float4*)(puB + lk);
    *(float4*)&puA[4]  = *(const float4*)(puB + lk + 4);
    *(float4*)&puA[8]  = *(const float4*)(puB + 32 + lk);
    *(float4*)&puA[12] = *(const float4*)(puB + 32 + lk + 4);
    *(float4*)&pvA[0]  = *(const float4*)(pvB + lk);
    *(float4*)&pvA[4]  = *(const float4*)(pvB + lk + 4);
    *(float4*)&pvA[8]  = *(const float4*)(pvB + 32 + lk);
    *(float4*)&pvA[12] = *(const float4*)(pvB + 32 + lk + 4);

    // ---- V pass-A + K gloads (stay in flight across qu/qv build) ----
#pragma unroll
    for (int g = 0; g < 3; ++g) {
        const int sp = w * 3 + g;
        gload_lds16(vsrc(sp), (char*)Vsub + sp * 1024);
    }
    {
        const int srow8 = lane >> 3;
        const int schunk = (lane & 7) ^ srow8;
#pragma unroll
        for (int g = 0; g < 6; ++g) {
            const int sp = w * 6 + g;
            if (sp < 22) {
                const int r = sp * 8 + srow8;
                int kb = t0 - HALFW + r; kb = kb < 0 ? 0 : (kb < TSEQ ? kb : TSEQ - 1);
                const ushort* src = qkv + (size_t)(b * TSEQ + kb) * QKVDIM + CDIM
                                    + h * DKK + schunk * 8;
                gload_lds16(src, (char*)Kl + sp * 1024);
            }
        }
    }

    // ---- build qu/qv first (frees the 32-reg pos arrays before pfr preload) ----
    s16x8 qu0, qu1, qv0, qv1;
#pragma unroll
    for (int e = 0; e < 8; ++e) {
        const float q0 = bf2f((ushort)qr0[e]), q1 = bf2f((ushort)qr1[e]);
        qu0[e] = (short)f2bf(q0 + puA[e]);
        qu1[e] = (short)f2bf(q1 + puA[8 + e]);
        qv0[e] = (short)f2bf(q0 + pvA[e]);
        qv1[e] = (short)f2bf(q1 + pvA[8 + e]);
    }

    // ---- rel-pos B-fragments straight from global (L2-hot) ----
    const ushort* pbh = pb + (size_t)949 * CDIM + h * DKK;
    s16x8 pfr[7][2];
#pragma unroll
    for (int uf = 0; uf < 7; ++uf) {
        pfr[uf][0] = *(const s16x8*)&pbh[(size_t)(uf * 16 + lr) * CDIM + lk];
        pfr[uf][1] = *(const s16x8*)&pbh[(size_t)(uf * 16 + lr) * CDIM + 32 + lk];
    }
    __syncthreads();

    const f32x4 zero = {0.f, 0.f, 0.f, 0.f};
    f32x4 acS[11], acB[7];
    __builtin_amdgcn_s_setprio(1);
#pragma unroll
    for (int uf = 0; uf < 7; ++uf) {
        acB[uf] = __builtin_amdgcn_mfma_f32_16x16x32_bf16(qv0, pfr[uf][0], zero, 0, 0, 0);
        acB[uf] = __builtin_amdgcn_mfma_f32_16x16x32_bf16(qv1, pfr[uf][1], acB[uf], 0, 0, 0);
    }
#pragma unroll
    for (int jf = 0; jf < 11; ++jf) {
        const int rr = jf * 16 + lr;
        const int sw = rr & 7;
        s16x8 k0 = *(const s16x8*)&Kl[rr * 64 + (((q)     ^ sw) << 3)];
        s16x8 k1 = *(const s16x8*)&Kl[rr * 64 + (((q | 4) ^ sw) << 3)];
        acS[jf] = __builtin_amdgcn_mfma_f32_16x16x32_bf16(qu0, k0, zero, 0, 0, 0);
        acS[jf] = __builtin_amdgcn_mfma_f32_16x16x32_bf16(qu1, k1, acS[jf], 0, 0, 0);
    }
    __builtin_amdgcn_s_setprio(0);

    ushort* bdw = Bd + w * 16 * 104;
#pragma unroll
    for (int uf = 0; uf < 7; ++uf)
#pragma unroll
        for (int r = 0; r < 4; ++r)
            bdw[((lane >> 4) * 4 + r) * 104 + uf * 16 + lr] = f2bf(acB[uf][r]);
    float mx[4] = {-1e30f, -1e30f, -1e30f, -1e30f};
#pragma unroll
    for (int jf = 0; jf < 11; ++jf)
#pragma unroll
        for (int r = 0; r < 4; ++r) {
            const int tl = (lane >> 4) * 4 + r;
            const int tloc = m0 + tl;
            const int j = jf * 16 + lr;
            const int u = j - tloc;
            const int s = t0 - HALFW + j;
            const bool valid = (u >= 0) & (u <= 2 * HALFW) & (s >= 0) & (s < TSEQ)
                               & (t0 + tloc < TSEQ);
            float sc = -1e30f;
            if (valid) sc = (acS[jf][r] + bf2f(bdw[tl * 104 + u])) * 0.125f;
            acS[jf][r] = sc;
            mx[r] = fmaxf(mx[r], sc);
        }
#pragma unroll
    for (int r = 0; r < 4; ++r)
#pragma unroll
        for (int off = 8; off; off >>= 1)
            mx[r] = fmaxf(mx[r], __shfl_xor(mx[r], off));
    float sm[4] = {0.f, 0.f, 0.f, 0.f};
#pragma unroll
    for (int jf = 0; jf < 11; ++jf)
#pragma unroll
        for (int r = 0; r < 4; ++r) {
            float e = __expf(acS[jf][r] - mx[r]);
            acS[jf][r] = e;
            sm[r] += e;
        }
#pragma unroll
    for (int r = 0; r < 4; ++r) {
#pragma unroll
        for (int off = 8; off; off >>= 1) sm[r] += __shfl_xor(sm[r], off);
        sm[r] = 1.f / sm[r];
    }
    __syncthreads();

    s16x8 vr0 = *vsrc(12 + w * 3 + 0);
    s16x8 vr1 = *vsrc(12 + w * 3 + 1);
    s16x8 vr2 = *vsrc(12 + w * 3 + 2);

#pragma unroll
    for (int jf = 0; jf < 11; ++jf)
#pragma unroll
        for (int r = 0; r < 4; ++r)
            Pl[(m0 + (lane >> 4) * 4 + r) * 200 + jf * 16 + lr] = f2bf(acS[jf][r]);
#pragma unroll
    for (int r = 0; r < 4; ++r)
        Pl[(m0 + (lane >> 4) * 4 + r) * 200 + 176 + lr] = 0;

    s16x8 pa[6];
#pragma unroll
    for (int ks = 0; ks < 6; ++ks)
        pa[ks] = *(const s16x8*)&Pl[(m0 + lr) * 200 + ks * 32 + lk];

    const unsigned vbase = LDSOFF(Vsub);
#pragma unroll
    for (int nf = 0; nf < 2; ++nf) {
        const unsigned abase = vbase + (nf & 1) * 6144 + ((lane >> 4) << 8) + ((lane & 15) << 1);
        s16x4 lo[6], hi[6];
#pragma unroll
        for (int ks = 0; ks < 6; ++ks) {
            lo[ks] = tr_read(abase + ks * 1024);
            hi[ks] = tr_read128(abase + ks * 1024);
        }
        asm volatile("s_waitcnt lgkmcnt(0)" ::: "memory");
        __builtin_amdgcn_sched_barrier(0);
        f32x4 acO = {};
        __builtin_amdgcn_s_setprio(1);
#pragma unroll
        for (int ks = 0; ks < 6; ++ks) {
            s16x8 vb = __builtin_shufflevector(lo[ks], hi[ks], 0, 1, 2, 3, 4, 5, 6, 7);
            acO = __builtin_amdgcn_mfma_f32_16x16x32_bf16(pa[ks], vb, acO, 0, 0, 0);
        }
        __builtin_amdgcn_s_setprio(0);
#pragma unroll
        for (int r = 0; r < 4; ++r) {
            const int t = t0 + m0 + (lane >> 4) * 4 + r;
            if (t < TSEQ)
                o[(size_t)(b * TSEQ + t) * CDIM + h * DKK + nf * 16 + lr] =
                    f2bf(acO[r] * sm[r]);
        }
    }
    __syncthreads();

    *(s16x8*)((char*)Vsub + (w * 3 + 0) * 1024 + lane * 16) = vr0;
    *(s16x8*)((char*)Vsub + (w * 3 + 1) * 1024 + lane * 16) = vr1;
    *(s16x8*)((char*)Vsub + (w * 3 + 2) * 1024 + lane * 16) = vr2;
    __syncthreads();

#pragma unroll
    for (int nf = 2; nf < 4; ++nf) {
        const unsigned abase = vbase + (nf & 1) * 6144 + ((lane >> 4) << 8) + ((lane & 15) << 1);
        s16x4 lo[6], hi[6];
#pragma unroll
        for (int ks = 0; ks < 6; ++ks) {
            lo[ks] = tr_read(abase + ks * 1024);
            hi[ks] = tr_read128(abase + ks * 1024);
        }
        asm volatile("s_waitcnt lgkmcnt(0)" ::: "memory");
        __builtin_amdgcn_sched_barrier(0);
        f32x4 acO = {};
        __builtin_amdgcn_s_setprio(1);
#pragma unroll
        for (int ks = 0; ks < 6; ++ks) {
            s16x8 vb = __builtin_shufflevector(lo[ks], hi[ks], 0, 1, 2, 3, 4, 5, 6, 7);
            acO = __builtin_amdgcn_mfma_f32_16x16x32_bf16(pa[ks], vb, acO, 0, 0, 0);
        }
        __builtin_amdgcn_s_setprio(0);
#pragma unroll
        for (int r = 0; r < 4; ++r) {
            const int t = t0 + m0 + (lane >> 4) * 4 + r;
            if (t < TSEQ)
                o[(size_t)(b * TSEQ + t) * CDIM + h * DKK + nf * 16 + lr] =
                    f2bf(acO[r] * sm[r]);
        }
    }
}

// ---------------- launch ----------------
extern "C" void kernel_launch(void* const* d_in, const int* in_sizes, int n_in,
                              void* d_out, int out_size, void* d_ws, size_t ws_size,
                              hipStream_t stream) {
    const float* x     = (const float*)d_in[0];
    const float* Wq    = (const float*)d_in[1];
    const float* bq    = (const float*)d_in[2];
    const float* Wk    = (const float*)d_in[3];
    const float* bk    = (const float*)d_in[4];
    const float* Wv    = (const float*)d_in[5];
    const float* bv    = (const float*)d_in[6];
    const float* Wo    = (const float*)d_in[7];
    const float* bo    = (const float*)d_in[8];
    const float* Wp    = (const float*)d_in[9];
    const float* pos_u = (const float*)d_in[10];
    const float* pos_v = (const float*)d_in[11];
    const float* ln1g  = (const float*)d_in[12];
    const float* ln1b  = (const float*)d_in[13];
    const float* ln2g  = (const float*)d_in[14];
    const float* ln2b  = (const float*)d_in[15];
    const float* W1    = (const float*)d_in[16];
    const float* b1    = (const float*)d_in[17];
    const float* W2    = (const float*)d_in[18];
    const float* b2    = (const float*)d_in[19];

    float* h = (float*)d_out;
    const float XS = 27.712812921102035f;   // sqrt(768)

    char* p = (char*)d_ws;
    ushort* Wtqkv = (ushort*)p;               p += (size_t)LNUM * QKVDIM * CDIM * 2;
    ushort* Wtp   = (ushort*)p;               p += (size_t)LNUM * CDIM * CDIM * 2;
    ushort* Wto   = (ushort*)p;               p += (size_t)LNUM * CDIM * CDIM * 2;
    ushort* Wt1   = (ushort*)p;               p += (size_t)LNUM * CDIM * CDIM * 2;
    ushort* Wt2   = (ushort*)p;               p += (size_t)LNUM * CDIM * CDIM * 2;
    float*  bqkv  = (float*)p;                p += (size_t)LNUM * QKVDIM * 4;
    ushort* pe    = (ushort*)p;               p += (size_t)2048 * CDIM * 2;
    ushort* pb    = (ushort*)p;               p += (size_t)LNUM * 2048 * CDIM * 2;
    ushort* y     = (ushort*)p;               p += (size_t)MPAD * CDIM * 2;
    ushort* qkv   = (ushort*)p;               p += (size_t)MPAD * QKVDIM * 2;
    ushort* o     = (ushort*)p;               p += (size_t)MPAD * CDIM * 2;
    ushort* hid   = (ushort*)p;               p += (size_t)MPAD * CDIM * 2;

    transpose_pack<<<dim3(24, 24, 15), dim3(8, 32), 0, stream>>>(
        Wq, Wk, Wv, Wp, Wo, W1, W2, Wtqkv, Wtp, Wto, Wt1, Wt2,
        pe, bq, bk, bv, bqkv);

    const int MB = (MROWS + 63) / 64;        // 63 row-blocks
    const dim3 gQKV(32, QKVDIM / 128);       // 128x128 tiles: (32, 18) = 576 blocks
    const dim3 gC(MB, CDIM / 128);           // (63, 6)
    const dim3 gP(4, CDIM / 128, LNUM);      // M=256 rel-pos rows, both layers
    const dim3 gA(16, HHEADS, BBATCH);

    gemm64<0><<<gP, 256, 0, stream>>>(pe + (size_t)896 * CDIM, Wtp, nullptr,
                                      pb + (size_t)896 * CDIM, 256, CDIM,
                                      nullptr, 0.f,
                                      (size_t)CDIM * CDIM, (size_t)2048 * CDIM);

    for (int l = 0; l < LNUM; ++l) {
        const size_t wo = (size_t)l * CDIM * CDIM;
        const float* res1 = (l == 0) ? x : h;
        const float rs1   = (l == 0) ? XS : 1.f;
        ln_kernel<<<MROWS, 192, 0, stream>>>(res1, ln1g + l * CDIM, ln1b + l * CDIM, y, rs1);
        gemm128<0><<<gQKV, 256, 0, stream>>>(y, Wtqkv + (size_t)l * QKVDIM * CDIM,
                                             bqkv + l * QKVDIM, qkv, MROWS, QKVDIM);
        attn_mfma<<<gA, 256, 0, stream>>>(
            qkv, pb + (size_t)l * 2048 * CDIM,
            pos_u + l * HHEADS * DKK, pos_v + l * HHEADS * DKK, o);
        gemm64<2><<<gC, 256, 0, stream>>>(o, Wto + wo, bo + l * CDIM, h, MROWS, CDIM,
                                          res1, rs1, 0, 0);
        ln_kernel<<<MROWS, 192, 0, stream>>>(h, ln2g + l * CDIM, ln2b + l * CDIM, y, 1.f);
        gemm64<1><<<gC, 256, 0, stream>>>(y, Wt1 + wo, b1 + l * CDIM, hid, MROWS, CDIM,
                                          nullptr, 0.f, 0, 0);
        gemm64<2><<<gC, 256, 0, stream>>>(hid, Wt2 + wo, b2 + l * CDIM, h, MROWS, CDIM,
                                          h, 1.f, 0, 0);
    }
}

// Round 14
// 244.743 us; speedup vs baseline: 1.4192x; 1.0084x over previous
//
#include <hip/hip_runtime.h>
#include <math.h>

#define LNUM 2
#define BBATCH 4
#define TSEQ 1000
#define CDIM 768
#define HHEADS 12
#define DKK 64
#define PPOS (2*TSEQ-1)   // 1999
#define HALFW 50
#define MROWS (BBATCH*TSEQ)     // 4000
#define MPAD 4096
#define QKVDIM (3*CDIM)         // 2304
#define NS 176                  // real key span per 64-query tile (padded to 192)

typedef __attribute__((ext_vector_type(8))) short s16x8;
typedef __attribute__((ext_vector_type(4))) short s16x4;
typedef __attribute__((ext_vector_type(4))) float f32x4;

#define LDSOFF(p) ((unsigned)(uintptr_t)(__attribute__((address_space(3))) const void*)(p))

__device__ __forceinline__ ushort f2bf(float x) {
    unsigned u = __float_as_uint(x);
    unsigned r = u + 0x7FFFu + ((u >> 16) & 1u);
    return (ushort)(r >> 16);
}
__device__ __forceinline__ float bf2f(ushort h) {
    return __uint_as_float(((unsigned)h) << 16);
}
__device__ __forceinline__ float gelu_f(float x) {
    float u = 0.7978845608028654f * (x + 0.044715f * x * x * x);
    return 0.5f * x * (1.f + tanhf(u));
}
__device__ __forceinline__ void gload_lds16(const void* g, void* l) {
    __builtin_amdgcn_global_load_lds(
        (const __attribute__((address_space(1))) void*)g,
        (__attribute__((address_space(3))) void*)l, 16, 0, 0);
}
__device__ __forceinline__ s16x4 tr_read(unsigned addr) {
    s16x4 d;
    asm volatile("ds_read_b64_tr_b16 %0, %1" : "=v"(d) : "v"(addr));
    return d;
}
__device__ __forceinline__ s16x4 tr_read128(unsigned addr) {
    s16x4 d;
    asm volatile("ds_read_b64_tr_b16 %0, %1 offset:128" : "=v"(d) : "v"(addr));
    return d;
}
// bijective XCD-chunked swizzle (m204): contiguous tile chunk per XCD
__device__ __forceinline__ int xcd_swz(int orig, int nwg) {
    const int xcd = orig & 7, ixc = orig >> 3;
    const int qq = nwg >> 3, rr = nwg & 7;
    return (xcd < rr ? xcd * (qq + 1) : rr * (qq + 1) + (xcd - rr) * qq) + ixc;
}

// ---------------- weight transpose + bf16 convert, fused with small prep ----------------
// z 0..13: weight slice l*7+m; z==14: pos-enc rows [896,1152) + qkv bias pack.
__global__ __launch_bounds__(256) void transpose_pack(
    const float* __restrict__ Wq, const float* __restrict__ Wk,
    const float* __restrict__ Wv, const float* __restrict__ Wp,
    const float* __restrict__ Wo, const float* __restrict__ W1,
    const float* __restrict__ W2,
    ushort* __restrict__ Wtqkv, ushort* __restrict__ Wtp,
    ushort* __restrict__ Wto, ushort* __restrict__ Wt1, ushort* __restrict__ Wt2,
    ushort* __restrict__ pe,
    const float* __restrict__ bq, const float* __restrict__ bk,
    const float* __restrict__ bv, float* __restrict__ bqkv) {
    const int tx = threadIdx.x, ty = threadIdx.y;       // (8, 32)
    if (blockIdx.z == 14) {
        const int linear = blockIdx.y * 24 + blockIdx.x;
        const int idx = linear * 256 + ty * 8 + tx;
        const int npair = 256 * (CDIM / 2);
        if (idx < npair) {
            int jloc = idx / (CDIM / 2);
            int m = idx - jloc * (CDIM / 2);
            int j = 896 + jloc;
            float rel = (float)(TSEQ - 1 - j);
            float div = expf(-(float)(2 * m) * (9.210340371976184f / (float)CDIM));
            float a = rel * div;
            pe[(size_t)j * CDIM + 2 * m]     = f2bf(sinf(a));
            pe[(size_t)j * CDIM + 2 * m + 1] = f2bf(cosf(a));
        }
        if (idx < LNUM * QKVDIM) {
            int l = idx / QKVDIM, c = idx - l * QKVDIM;
            float v;
            if (c < CDIM)            v = bq[l * CDIM + c];
            else if (c < 2 * CDIM)   v = bk[l * CDIM + c - CDIM];
            else                     v = bv[l * CDIM + c - 2 * CDIM];
            bqkv[idx] = v;
        }
        return;
    }
    const int l = blockIdx.z / 7, m = blockIdx.z % 7;
    const float* srcs[7] = {Wq, Wk, Wv, Wp, Wo, W1, W2};
    const float* src = srcs[m] + (size_t)l * CDIM * CDIM;
    ushort* dst;
    if (m < 3)       dst = Wtqkv + (size_t)l * QKVDIM * CDIM + (size_t)m * CDIM * CDIM;
    else if (m == 3) dst = Wtp + (size_t)l * CDIM * CDIM;
    else if (m == 4) dst = Wto + (size_t)l * CDIM * CDIM;
    else if (m == 5) dst = Wt1 + (size_t)l * CDIM * CDIM;
    else             dst = Wt2 + (size_t)l * CDIM * CDIM;
    __shared__ float tile[32][33];
    const int c0 = blockIdx.x * 32, r0 = blockIdx.y * 32;
    const float4 v = *(const float4*)&src[(size_t)(r0 + ty) * CDIM + c0 + tx * 4];
    tile[tx * 4 + 0][ty] = v.x;
    tile[tx * 4 + 1][ty] = v.y;
    tile[tx * 4 + 2][ty] = v.z;
    tile[tx * 4 + 3][ty] = v.w;
    __syncthreads();
    const float a0 = tile[ty][tx * 4 + 0], a1 = tile[ty][tx * 4 + 1];
    const float a2 = tile[ty][tx * 4 + 2], a3 = tile[ty][tx * 4 + 3];
    uint2 pk;
    pk.x = (unsigned)f2bf(a0) | ((unsigned)f2bf(a1) << 16);
    pk.y = (unsigned)f2bf(a2) | ((unsigned)f2bf(a3) << 16);
    *(uint2*)&dst[(size_t)(c0 + ty) * CDIM + r0 + tx * 4] = pk;
}

// ---------------- LayerNorm: wave-per-row, no LDS/barrier; f32 in (xscale), bf16 out ----
// 256 threads = 4 waves = 4 rows/block; lane covers cols {lane*4, 256+lane*4, 512+lane*4}.
__global__ __launch_bounds__(256) void ln_kernel(const float* __restrict__ in,
                                                 const float* __restrict__ g,
                                                 const float* __restrict__ bta,
                                                 ushort* __restrict__ y, float xscale) {
    const int w = threadIdx.x >> 6, lane = threadIdx.x & 63;
    const int row = blockIdx.x * 4 + w;
    const float* xr = in + (size_t)row * CDIM;
    float4 v0 = *(const float4*)&xr[lane * 4];
    float4 v1 = *(const float4*)&xr[256 + lane * 4];
    float4 v2 = *(const float4*)&xr[512 + lane * 4];
    v0.x *= xscale; v0.y *= xscale; v0.z *= xscale; v0.w *= xscale;
    v1.x *= xscale; v1.y *= xscale; v1.z *= xscale; v1.w *= xscale;
    v2.x *= xscale; v2.y *= xscale; v2.z *= xscale; v2.w *= xscale;
    float s  = v0.x + v0.y + v0.z + v0.w + v1.x + v1.y + v1.z + v1.w
             + v2.x + v2.y + v2.z + v2.w;
    float ss = v0.x * v0.x + v0.y * v0.y + v0.z * v0.z + v0.w * v0.w
             + v1.x * v1.x + v1.y * v1.y + v1.z * v1.z + v1.w * v1.w
             + v2.x * v2.x + v2.y * v2.y + v2.z * v2.z + v2.w * v2.w;
#pragma unroll
    for (int off = 32; off; off >>= 1) {
        s  += __shfl_xor(s, off);
        ss += __shfl_xor(ss, off);
    }
    const float mean = s * (1.f / CDIM);
    const float var  = ss * (1.f / CDIM) - mean * mean;
    const float rstd = rsqrtf(var + 1e-5f);
    ushort* yr = y + (size_t)row * CDIM;
#pragma unroll
    for (int c = 0; c < 3; ++c) {
        const int col = c * 256 + lane * 4;
        const float4 vv = (c == 0) ? v0 : (c == 1) ? v1 : v2;
        const float4 g4 = *(const float4*)&g[col];
        const float4 b4 = *(const float4*)&bta[col];
        ushort o0 = f2bf((vv.x - mean) * rstd * g4.x + b4.x);
        ushort o1 = f2bf((vv.y - mean) * rstd * g4.y + b4.y);
        ushort o2 = f2bf((vv.z - mean) * rstd * g4.z + b4.z);
        ushort o3 = f2bf((vv.w - mean) * rstd * g4.w + b4.w);
        uint2 pk; pk.x = (unsigned)o0 | ((unsigned)o1 << 16);
        pk.y = (unsigned)o2 | ((unsigned)o3 << 16);
        *(uint2*)&yr[col] = pk;
    }
}

// ---------------- MFMA bf16 GEMM: 64x128 tile, BK=64, dbuf, XCD-swizzled ----------------
template <int EPI>
__global__ __launch_bounds__(256, 3) void gemm64(const ushort* __restrict__ A,
                                                 const ushort* __restrict__ Bt,
                                                 const float* __restrict__ bias,
                                                 void* Out, int M, int ldo,
                                                 const float* resid, float rscale,
                                                 size_t zsB, size_t zsO) {
    __shared__ ushort lds[24576];              // 2 x 24 KB
    const int tid = threadIdx.x;
    const int w = tid >> 6, lane = tid & 63;
    const int nwg = gridDim.x * gridDim.y;
    const int newid = xcd_swz(blockIdx.y * gridDim.x + blockIdx.x, nwg);
    const int col0 = (newid % gridDim.y) * 128;     // col-fastest: XCD keeps B panels hot
    const int row0 = (newid / gridDim.y) * 64;
    const size_t zb = blockIdx.z;
    Bt += zb * zsB;
    if (EPI == 2) Out = (void*)((float*)Out + zb * zsO);
    else          Out = (void*)((ushort*)Out + zb * zsO);

    const int srow8  = lane >> 3;
    const int schunk = (lane & 7) ^ srow8;

#define STAGE64(buf, k0)                                                        \
    {                                                                           \
        _Pragma("unroll")                                                       \
        for (int g = 0; g < 6; ++g) {                                           \
            const int grp = w * 6 + g;                                          \
            const int r = grp * 8 + srow8;                                      \
            const ushort* src = (grp < 8)                                       \
                ? A  + (size_t)(row0 + r) * CDIM + (k0) + schunk * 8            \
                : Bt + (size_t)(col0 + (r - 64)) * CDIM + (k0) + schunk * 8;    \
            gload_lds16(src, (char*)lds + (buf) * 24576 + grp * 1024);          \
        }                                                                       \
    }

    const int wm = (w >> 1) * 32, wn = (w & 1) * 64;
    const int lr = lane & 15, q = lane >> 4;
    f32x4 acc[2][4] = {};

    STAGE64(0, 0);
    __syncthreads();
    int cur = 0;
    for (int k0 = 0; k0 < CDIM; k0 += 64) {
        if (k0 + 64 < CDIM) STAGE64(cur ^ 1, k0 + 64);
        const int base = cur * 12288;
#pragma unroll
        for (int kk = 0; kk < 2; ++kk) {
            s16x8 af[2], bfr[4];
#pragma unroll
            for (int i = 0; i < 2; ++i) {
                const int r = wm + i * 16 + lr;
                af[i] = *(const s16x8*)&lds[base + r * 64 + ((((kk << 2) | q) ^ (r & 7)) << 3)];
            }
#pragma unroll
            for (int j = 0; j < 4; ++j) {
                const int r = 64 + wn + j * 16 + lr;
                bfr[j] = *(const s16x8*)&lds[base + r * 64 + ((((kk << 2) | q) ^ (r & 7)) << 3)];
            }
#pragma unroll
            for (int i = 0; i < 2; ++i)
#pragma unroll
                for (int j = 0; j < 4; ++j)
                    acc[i][j] = __builtin_amdgcn_mfma_f32_16x16x32_bf16(af[i], bfr[j], acc[i][j], 0, 0, 0);
        }
        __syncthreads();
        cur ^= 1;
    }
#undef STAGE64

    const int lrr = (lane >> 4) * 4;
    const int lc = lane & 15;
#pragma unroll
    for (int j = 0; j < 4; ++j) {
        const int col = col0 + wn + j * 16 + lc;
        const float bv = bias ? bias[col] : 0.f;
#pragma unroll
        for (int i = 0; i < 2; ++i) {
#pragma unroll
            for (int r = 0; r < 4; ++r) {
                const int row = row0 + wm + i * 16 + lrr + r;
                if (row >= M) continue;
                const float v = acc[i][j][r] + bv;
                if (EPI == 0)
                    ((ushort*)Out)[(size_t)row * ldo + col] = f2bf(v);
                else if (EPI == 1)
                    ((ushort*)Out)[(size_t)row * ldo + col] = f2bf(gelu_f(v));
                else {
                    float* p = (float*)Out + (size_t)row * ldo + col;
                    *p = resid[(size_t)row * ldo + col] * rscale + v;
                }
            }
        }
    }
}

// ---------------- MFMA bf16 GEMM: 128x128 tile, BK=32, dbuf, XCD-swizzled ----------------
template <int EPI>
__global__ __launch_bounds__(256, 3) void gemm128(const ushort* __restrict__ A,
                                                  const ushort* __restrict__ Bt,
                                                  const float* __restrict__ bias,
                                                  void* Out, int M, int ldo) {
    __shared__ ushort lds[16384];              // 2 x 16 KB
    const int tid = threadIdx.x;
    const int w = tid >> 6, lane = tid & 63;
    const int nwg = gridDim.x * gridDim.y;
    const int newid = xcd_swz(blockIdx.y * gridDim.x + blockIdx.x, nwg);
    const int col0 = (newid % gridDim.y) * 128;
    const int row0 = (newid / gridDim.y) * 128;
    const int srow   = lane >> 2;
    const int schunk = (lane & 3) ^ ((lane >> 3) & 3);
    const int wm = (w >> 1) * 64, wn = (w & 1) * 64;
    const int lr = lane & 15, q = lane >> 4;

#define STAGE128(buf, k0)                                                       \
    {                                                                           \
        _Pragma("unroll")                                                       \
        for (int g = 0; g < 4; ++g) {                                           \
            const int sp = w * 4 + g;                                           \
            const int r = sp * 16 + srow;                                       \
            const ushort* src = (r < 128)                                       \
                ? A  + (size_t)(row0 + r) * CDIM + (k0) + schunk * 8            \
                : Bt + (size_t)(col0 + (r - 128)) * CDIM + (k0) + schunk * 8;   \
            gload_lds16(src, (char*)lds + (buf) * 16384 + sp * 1024);           \
        }                                                                       \
    }

    f32x4 acc[4][4] = {};
    STAGE128(0, 0);
    __syncthreads();
    int cur = 0;
    for (int k0 = 0; k0 < CDIM; k0 += 32) {
        if (k0 + 32 < CDIM) STAGE128(cur ^ 1, k0 + 32);
        const int base = cur * 8192;
        s16x8 af[4], bfr[4];
#pragma unroll
        for (int i = 0; i < 4; ++i) {
            const int r = wm + i * 16 + lr;
            af[i] = *(const s16x8*)&lds[base + r * 32 + ((q ^ ((r >> 1) & 3)) << 3)];
        }
#pragma unroll
        for (int j = 0; j < 4; ++j) {
            const int r = 128 + wn + j * 16 + lr;
            bfr[j] = *(const s16x8*)&lds[base + r * 32 + ((q ^ ((r >> 1) & 3)) << 3)];
        }
#pragma unroll
        for (int i = 0; i < 4; ++i)
#pragma unroll
            for (int j = 0; j < 4; ++j)
                acc[i][j] = __builtin_amdgcn_mfma_f32_16x16x32_bf16(af[i], bfr[j], acc[i][j], 0, 0, 0);
        __syncthreads();
        cur ^= 1;
    }
#undef STAGE128

    const int crow0 = row0 + (w >> 1) * 64;
    const int ccol0 = col0 + (w & 1) * 64;
    const int lrr = (lane >> 4) * 4;
    const int lc = lane & 15;
#pragma unroll
    for (int j = 0; j < 4; ++j) {
        const int col = ccol0 + j * 16 + lc;
        const float bv = bias ? bias[col] : 0.f;
#pragma unroll
        for (int i = 0; i < 4; ++i) {
#pragma unroll
            for (int r = 0; r < 4; ++r) {
                const int row = crow0 + i * 16 + lrr + r;
                if (row >= M) continue;
                const float v = acc[i][j][r] + bv;
                if (EPI == 0)
                    ((ushort*)Out)[(size_t)row * ldo + col] = f2bf(v);
                else if (EPI == 1)
                    ((ushort*)Out)[(size_t)row * ldo + col] = f2bf(gelu_f(v));
            }
        }
    }
}

// ---------------- MFMA banded rel-pos attention (round-8 structure, reg-pressure reorder) ----------------
__global__ __launch_bounds__(256, 3) void attn_mfma(
    const ushort* __restrict__ qkv, const ushort* __restrict__ pb,
    const float* __restrict__ pos_u, const float* __restrict__ pos_v,
    ushort* __restrict__ o) {
    __shared__ __align__(16) char smem[51200];
    ushort* Kl   = (ushort*)smem;               // [176][64] swizzled
    ushort* Pl   = (ushort*)smem;               // phase2 [64][200]
    ushort* Vsub = (ushort*)(smem + 25600);     // [2][192][16]
    ushort* Bd   = (ushort*)(smem + 37888);     // [4][16][104]

    const int tid = threadIdx.x;
    const int w = tid >> 6, lane = tid & 63;
    const int t0 = blockIdx.x * 64;
    const int h = blockIdx.y, b = blockIdx.z;
    const int m0 = w * 16;
    const int lr = lane & 15, lk = (lane >> 4) * 8, q = lane >> 4;

    auto vsrc = [&](int sp) -> const ushort* {
        const int ob = sp * 1024 + lane * 16;
        const int d0c = ob / 6144;
        const int rem = ob - d0c * 6144;
        const int j = rem >> 5;
        const int halfo = (rem & 31) >> 4;
        int t = t0 - HALFW + j; t = t < 0 ? 0 : (t < TSEQ ? t : TSEQ - 1);
        return qkv + (size_t)(b * TSEQ + t) * QKVDIM + 2 * CDIM + h * DKK
               + (d0c & 1) * 16 + halfo * 8;
    };

    // ---- Q + pos loads (oldest VMEM) ----
    int tq = t0 + m0 + lr; tq = tq < TSEQ ? tq : TSEQ - 1;
    const ushort* qp = qkv + (size_t)(b * TSEQ + tq) * QKVDIM + h * DKK;
    s16x8 qr0 = *(const s16x8*)(qp + lk);
    s16x8 qr1 = *(const s16x8*)(qp + 32 + lk);
    const float* puB = pos_u + h * DKK;
    const float* pvB = pos_v + h * DKK;
    float puA[16], pvA[16];
    *(float4*)&puA[0]  = *(const float4*)(puB + lk);
    *(float4*)&puA[4]  = *(const float4*)(puB + lk + 4);
    *(float4*)&puA[8]  = *(const float4*)(puB + 32 + lk);
    *(float4*)&puA[12] = *(const float4*)(puB + 32 + lk + 4);
    *(float4*)&pvA[0]  = *(const float4*)(pvB + lk);
    *(float4*)&pvA[4]  = *(const float4*)(pvB + lk + 4);
    *(float4*)&pvA[8]  = *(const float4*)(pvB + 32 + lk);
    *(float4*)&pvA[12] = *(const float4*)(pvB + 32 + lk + 4);

    // ---- V pass-A + K gloads (stay in flight across qu/qv build) ----
#pragma unroll
    for (int g = 0; g < 3; ++g) {
        const int sp = w * 3 + g;
        gload_lds16(vsrc(sp), (char*)Vsub + sp * 1024);
    }
    {
        const int srow8 = lane >> 3;
        const int schunk = (lane & 7) ^ srow8;
#pragma unroll
        for (int g = 0; g < 6; ++g) {
            const int sp = w * 6 + g;
            if (sp < 22) {
                const int r = sp * 8 + srow8;
                int kb = t0 - HALFW + r; kb = kb < 0 ? 0 : (kb < TSEQ ? kb : TSEQ - 1);
                const ushort* src = qkv + (size_t)(b * TSEQ + kb) * QKVDIM + CDIM
                                    + h * DKK + schunk * 8;
                gload_lds16(src, (char*)Kl + sp * 1024);
            }
        }
    }

    // ---- build qu/qv first (frees the 32-reg pos arrays before pfr preload) ----
    s16x8 qu0, qu1, qv0, qv1;
#pragma unroll
    for (int e = 0; e < 8; ++e) {
        const float q0 = bf2f((ushort)qr0[e]), q1 = bf2f((ushort)qr1[e]);
        qu0[e] = (short)f2bf(q0 + puA[e]);
        qu1[e] = (short)f2bf(q1 + puA[8 + e]);
        qv0[e] = (short)f2bf(q0 + pvA[e]);
        qv1[e] = (short)f2bf(q1 + pvA[8 + e]);
    }

    // ---- rel-pos B-fragments straight from global (L2-hot) ----
    const ushort* pbh = pb + (size_t)949 * CDIM + h * DKK;
    s16x8 pfr[7][2];
#pragma unroll
    for (int uf = 0; uf < 7; ++uf) {
        pfr[uf][0] = *(const s16x8*)&pbh[(size_t)(uf * 16 + lr) * CDIM + lk];
        pfr[uf][1] = *(const s16x8*)&pbh[(size_t)(uf * 16 + lr) * CDIM + 32 + lk];
    }
    __syncthreads();

    const f32x4 zero = {0.f, 0.f, 0.f, 0.f};
    f32x4 acS[11], acB[7];
    __builtin_amdgcn_s_setprio(1);
#pragma unroll
    for (int uf = 0; uf < 7; ++uf) {
        acB[uf] = __builtin_amdgcn_mfma_f32_16x16x32_bf16(qv0, pfr[uf][0], zero, 0, 0, 0);
        acB[uf] = __builtin_amdgcn_mfma_f32_16x16x32_bf16(qv1, pfr[uf][1], acB[uf], 0, 0, 0);
    }
#pragma unroll
    for (int jf = 0; jf < 11; ++jf) {
        const int rr = jf * 16 + lr;
        const int sw = rr & 7;
        s16x8 k0 = *(const s16x8*)&Kl[rr * 64 + (((q)     ^ sw) << 3)];
        s16x8 k1 = *(const s16x8*)&Kl[rr * 64 + (((q | 4) ^ sw) << 3)];
        acS[jf] = __builtin_amdgcn_mfma_f32_16x16x32_bf16(qu0, k0, zero, 0, 0, 0);
        acS[jf] = __builtin_amdgcn_mfma_f32_16x16x32_bf16(qu1, k1, acS[jf], 0, 0, 0);
    }
    __builtin_amdgcn_s_setprio(0);

    ushort* bdw = Bd + w * 16 * 104;
#pragma unroll
    for (int uf = 0; uf < 7; ++uf)
#pragma unroll
        for (int r = 0; r < 4; ++r)
            bdw[((lane >> 4) * 4 + r) * 104 + uf * 16 + lr] = f2bf(acB[uf][r]);
    float mx[4] = {-1e30f, -1e30f, -1e30f, -1e30f};
#pragma unroll
    for (int jf = 0; jf < 11; ++jf)
#pragma unroll
        for (int r = 0; r < 4; ++r) {
            const int tl = (lane >> 4) * 4 + r;
            const int tloc = m0 + tl;
            const int j = jf * 16 + lr;
            const int u = j - tloc;
            const int s = t0 - HALFW + j;
            const bool valid = (u >= 0) & (u <= 2 * HALFW) & (s >= 0) & (s < TSEQ)
                               & (t0 + tloc < TSEQ);
            float sc = -1e30f;
            if (valid) sc = (acS[jf][r] + bf2f(bdw[tl * 104 + u])) * 0.125f;
            acS[jf][r] = sc;
            mx[r] = fmaxf(mx[r], sc);
        }
#pragma unroll
    for (int r = 0; r < 4; ++r)
#pragma unroll
        for (int off = 8; off; off >>= 1)
            mx[r] = fmaxf(mx[r], __shfl_xor(mx[r], off));
    float sm[4] = {0.f, 0.f, 0.f, 0.f};
#pragma unroll
    for (int jf = 0; jf < 11; ++jf)
#pragma unroll
        for (int r = 0; r < 4; ++r) {
            float e = __expf(acS[jf][r] - mx[r]);
            acS[jf][r] = e;
            sm[r] += e;
        }
#pragma unroll
    for (int r = 0; r < 4; ++r) {
#pragma unroll
        for (int off = 8; off; off >>= 1) sm[r] += __shfl_xor(sm[r], off);
        sm[r] = 1.f / sm[r];
    }
    __syncthreads();

    s16x8 vr0 = *vsrc(12 + w * 3 + 0);
    s16x8 vr1 = *vsrc(12 + w * 3 + 1);
    s16x8 vr2 = *vsrc(12 + w * 3 + 2);

#pragma unroll
    for (int jf = 0; jf < 11; ++jf)
#pragma unroll
        for (int r = 0; r < 4; ++r)
            Pl[(m0 + (lane >> 4) * 4 + r) * 200 + jf * 16 + lr] = f2bf(acS[jf][r]);
#pragma unroll
    for (int r = 0; r < 4; ++r)
        Pl[(m0 + (lane >> 4) * 4 + r) * 200 + 176 + lr] = 0;

    s16x8 pa[6];
#pragma unroll
    for (int ks = 0; ks < 6; ++ks)
        pa[ks] = *(const s16x8*)&Pl[(m0 + lr) * 200 + ks * 32 + lk];

    const unsigned vbase = LDSOFF(Vsub);
#pragma unroll
    for (int nf = 0; nf < 2; ++nf) {
        const unsigned abase = vbase + (nf & 1) * 6144 + ((lane >> 4) << 8) + ((lane & 15) << 1);
        s16x4 lo[6], hi[6];
#pragma unroll
        for (int ks = 0; ks < 6; ++ks) {
            lo[ks] = tr_read(abase + ks * 1024);
            hi[ks] = tr_read128(abase + ks * 1024);
        }
        asm volatile("s_waitcnt lgkmcnt(0)" ::: "memory");
        __builtin_amdgcn_sched_barrier(0);
        f32x4 acO = {};
        __builtin_amdgcn_s_setprio(1);
#pragma unroll
        for (int ks = 0; ks < 6; ++ks) {
            s16x8 vb = __builtin_shufflevector(lo[ks], hi[ks], 0, 1, 2, 3, 4, 5, 6, 7);
            acO = __builtin_amdgcn_mfma_f32_16x16x32_bf16(pa[ks], vb, acO, 0, 0, 0);
        }
        __builtin_amdgcn_s_setprio(0);
#pragma unroll
        for (int r = 0; r < 4; ++r) {
            const int t = t0 + m0 + (lane >> 4) * 4 + r;
            if (t < TSEQ)
                o[(size_t)(b * TSEQ + t) * CDIM + h * DKK + nf * 16 + lr] =
                    f2bf(acO[r] * sm[r]);
        }
    }
    __syncthreads();

    *(s16x8*)((char*)Vsub + (w * 3 + 0) * 1024 + lane * 16) = vr0;
    *(s16x8*)((char*)Vsub + (w * 3 + 1) * 1024 + lane * 16) = vr1;
    *(s16x8*)((char*)Vsub + (w * 3 + 2) * 1024 + lane * 16) = vr2;
    __syncthreads();

#pragma unroll
    for (int nf = 2; nf < 4; ++nf) {
        const unsigned abase = vbase + (nf & 1) * 6144 + ((lane >> 4) << 8) + ((lane & 15) << 1);
        s16x4 lo[6], hi[6];
#pragma unroll
        for (int ks = 0; ks < 6; ++ks) {
            lo[ks] = tr_read(abase + ks * 1024);
            hi[ks] = tr_read128(abase + ks * 1024);
        }
        asm volatile("s_waitcnt lgkmcnt(0)" ::: "memory");
        __builtin_amdgcn_sched_barrier(0);
        f32x4 acO = {};
        __builtin_amdgcn_s_setprio(1);
#pragma unroll
        for (int ks = 0; ks < 6; ++ks) {
            s16x8 vb = __builtin_shufflevector(lo[ks], hi[ks], 0, 1, 2, 3, 4, 5, 6, 7);
            acO = __builtin_amdgcn_mfma_f32_16x16x32_bf16(pa[ks], vb, acO, 0, 0, 0);
        }
        __builtin_amdgcn_s_setprio(0);
#pragma unroll
        for (int r = 0; r < 4; ++r) {
            const int t = t0 + m0 + (lane >> 4) * 4 + r;
            if (t < TSEQ)
                o[(size_t)(b * TSEQ + t) * CDIM + h * DKK + nf * 16 + lr] =
                    f2bf(acO[r] * sm[r]);
        }
    }
}

// ---------------- launch ----------------
extern "C" void kernel_launch(void* const* d_in, const int* in_sizes, int n_in,
                              void* d_out, int out_size, void* d_ws, size_t ws_size,
                              hipStream_t stream) {
    const float* x     = (const float*)d_in[0];
    const float* Wq    = (const float*)d_in[1];
    const float* bq    = (const float*)d_in[2];
    const float* Wk    = (const float*)d_in[3];
    const float* bk    = (const float*)d_in[4];
    const float* Wv    = (const float*)d_in[5];
    const float* bv    = (const float*)d_in[6];
    const float* Wo    = (const float*)d_in[7];
    const float* bo    = (const float*)d_in[8];
    const float* Wp    = (const float*)d_in[9];
    const float* pos_u = (const float*)d_in[10];
    const float* pos_v = (const float*)d_in[11];
    const float* ln1g  = (const float*)d_in[12];
    const float* ln1b  = (const float*)d_in[13];
    const float* ln2g  = (const float*)d_in[14];
    const float* ln2b  = (const float*)d_in[15];
    const float* W1    = (const float*)d_in[16];
    const float* b1    = (const float*)d_in[17];
    const float* W2    = (const float*)d_in[18];
    const float* b2    = (const float*)d_in[19];

    float* h = (float*)d_out;
    const float XS = 27.712812921102035f;   // sqrt(768)

    char* p = (char*)d_ws;
    ushort* Wtqkv = (ushort*)p;               p += (size_t)LNUM * QKVDIM * CDIM * 2;
    ushort* Wtp   = (ushort*)p;               p += (size_t)LNUM * CDIM * CDIM * 2;
    ushort* Wto   = (ushort*)p;               p += (size_t)LNUM * CDIM * CDIM * 2;
    ushort* Wt1   = (ushort*)p;               p += (size_t)LNUM * CDIM * CDIM * 2;
    ushort* Wt2   = (ushort*)p;               p += (size_t)LNUM * CDIM * CDIM * 2;
    float*  bqkv  = (float*)p;                p += (size_t)LNUM * QKVDIM * 4;
    ushort* pe    = (ushort*)p;               p += (size_t)2048 * CDIM * 2;
    ushort* pb    = (ushort*)p;               p += (size_t)LNUM * 2048 * CDIM * 2;
    ushort* y     = (ushort*)p;               p += (size_t)MPAD * CDIM * 2;
    ushort* qkv   = (ushort*)p;               p += (size_t)MPAD * QKVDIM * 2;
    ushort* o     = (ushort*)p;               p += (size_t)MPAD * CDIM * 2;
    ushort* hid   = (ushort*)p;               p += (size_t)MPAD * CDIM * 2;

    transpose_pack<<<dim3(24, 24, 15), dim3(8, 32), 0, stream>>>(
        Wq, Wk, Wv, Wp, Wo, W1, W2, Wtqkv, Wtp, Wto, Wt1, Wt2,
        pe, bq, bk, bv, bqkv);

    const int MB = (MROWS + 63) / 64;        // 63 row-blocks
    const dim3 gQKV(32, QKVDIM / 128);       // 128x128 tiles: (32, 18) = 576 blocks
    const dim3 gC(MB, CDIM / 128);           // (63, 6)
    const dim3 gP(4, CDIM / 128, LNUM);      // M=256 rel-pos rows, both layers
    const dim3 gA(16, HHEADS, BBATCH);

    gemm64<0><<<gP, 256, 0, stream>>>(pe + (size_t)896 * CDIM, Wtp, nullptr,
                                      pb + (size_t)896 * CDIM, 256, CDIM,
                                      nullptr, 0.f,
                                      (size_t)CDIM * CDIM, (size_t)2048 * CDIM);

    for (int l = 0; l < LNUM; ++l) {
        const size_t wo = (size_t)l * CDIM * CDIM;
        const float* res1 = (l == 0) ? x : h;
        const float rs1   = (l == 0) ? XS : 1.f;
        ln_kernel<<<MROWS / 4, 256, 0, stream>>>(res1, ln1g + l * CDIM, ln1b + l * CDIM, y, rs1);
        gemm128<0><<<gQKV, 256, 0, stream>>>(y, Wtqkv + (size_t)l * QKVDIM * CDIM,
                                             bqkv + l * QKVDIM, qkv, MROWS, QKVDIM);
        attn_mfma<<<gA, 256, 0, stream>>>(
            qkv, pb + (size_t)l * 2048 * CDIM,
            pos_u + l * HHEADS * DKK, pos_v + l * HHEADS * DKK, o);
        gemm64<2><<<gC, 256, 0, stream>>>(o, Wto + wo, bo + l * CDIM, h, MROWS, CDIM,
                                          res1, rs1, 0, 0);
        ln_kernel<<<MROWS / 4, 256, 0, stream>>>(h, ln2g + l * CDIM, ln2b + l * CDIM, y, 1.f);
        gemm64<1><<<gC, 256, 0, stream>>>(y, Wt1 + wo, b1 + l * CDIM, hid, MROWS, CDIM,
                                          nullptr, 0.f, 0, 0);
        gemm64<2><<<gC, 256, 0, stream>>>(hid, Wt2 + wo, b2 + l * CDIM, h, MROWS, CDIM,
                                          h, 1.f, 0, 0);
    }
}

// Round 15
// 217.744 us; speedup vs baseline: 1.5952x; 1.1240x over previous
//
#include <hip/hip_runtime.h>
#include <math.h>

#define LNUM 2
#define BBATCH 4
#define TSEQ 1000
#define CDIM 768
#define HHEADS 12
#define DKK 64
#define PPOS (2*TSEQ-1)   // 1999
#define HALFW 50
#define MROWS (BBATCH*TSEQ)     // 4000
#define MPAD 4096
#define QKVDIM (3*CDIM)         // 2304
#define NS 176                  // real key span per 64-query tile (padded to 192)

typedef __attribute__((ext_vector_type(8))) short s16x8;
typedef __attribute__((ext_vector_type(4))) short s16x4;
typedef __attribute__((ext_vector_type(4))) float f32x4;

#define LDSOFF(p) ((unsigned)(uintptr_t)(__attribute__((address_space(3))) const void*)(p))

__device__ __forceinline__ ushort f2bf(float x) {
    unsigned u = __float_as_uint(x);
    unsigned r = u + 0x7FFFu + ((u >> 16) & 1u);
    return (ushort)(r >> 16);
}
__device__ __forceinline__ float bf2f(ushort h) {
    return __uint_as_float(((unsigned)h) << 16);
}
__device__ __forceinline__ float gelu_f(float x) {
    float u = 0.7978845608028654f * (x + 0.044715f * x * x * x);
    return 0.5f * x * (1.f + tanhf(u));
}
__device__ __forceinline__ void gload_lds16(const void* g, void* l) {
    __builtin_amdgcn_global_load_lds(
        (const __attribute__((address_space(1))) void*)g,
        (__attribute__((address_space(3))) void*)l, 16, 0, 0);
}
__device__ __forceinline__ s16x4 tr_read(unsigned addr) {
    s16x4 d;
    asm volatile("ds_read_b64_tr_b16 %0, %1" : "=v"(d) : "v"(addr));
    return d;
}
__device__ __forceinline__ s16x4 tr_read128(unsigned addr) {
    s16x4 d;
    asm volatile("ds_read_b64_tr_b16 %0, %1 offset:128" : "=v"(d) : "v"(addr));
    return d;
}
// bijective XCD-chunked swizzle (m204): contiguous tile chunk per XCD
__device__ __forceinline__ int xcd_swz(int orig, int nwg) {
    const int xcd = orig & 7, ixc = orig >> 3;
    const int qq = nwg >> 3, rr = nwg & 7;
    return (xcd < rr ? xcd * (qq + 1) : rr * (qq + 1) + (xcd - rr) * qq) + ixc;
}

// ---------------- weight transpose + bf16 convert, fused with small prep ----------------
// z 0..13: weight slice l*7+m; z==14: pos-enc rows [896,1152) + qkv bias pack.
__global__ __launch_bounds__(256) void transpose_pack(
    const float* __restrict__ Wq, const float* __restrict__ Wk,
    const float* __restrict__ Wv, const float* __restrict__ Wp,
    const float* __restrict__ Wo, const float* __restrict__ W1,
    const float* __restrict__ W2,
    ushort* __restrict__ Wtqkv, ushort* __restrict__ Wtp,
    ushort* __restrict__ Wto, ushort* __restrict__ Wt1, ushort* __restrict__ Wt2,
    ushort* __restrict__ pe,
    const float* __restrict__ bq, const float* __restrict__ bk,
    const float* __restrict__ bv, float* __restrict__ bqkv) {
    const int tx = threadIdx.x, ty = threadIdx.y;       // (8, 32)
    if (blockIdx.z == 14) {
        const int linear = blockIdx.y * 24 + blockIdx.x;
        const int idx = linear * 256 + ty * 8 + tx;
        const int npair = 256 * (CDIM / 2);
        if (idx < npair) {
            int jloc = idx / (CDIM / 2);
            int m = idx - jloc * (CDIM / 2);
            int j = 896 + jloc;
            float rel = (float)(TSEQ - 1 - j);
            float div = expf(-(float)(2 * m) * (9.210340371976184f / (float)CDIM));
            float a = rel * div;
            pe[(size_t)j * CDIM + 2 * m]     = f2bf(sinf(a));
            pe[(size_t)j * CDIM + 2 * m + 1] = f2bf(cosf(a));
        }
        if (idx < LNUM * QKVDIM) {
            int l = idx / QKVDIM, c = idx - l * QKVDIM;
            float v;
            if (c < CDIM)            v = bq[l * CDIM + c];
            else if (c < 2 * CDIM)   v = bk[l * CDIM + c - CDIM];
            else                     v = bv[l * CDIM + c - 2 * CDIM];
            bqkv[idx] = v;
        }
        return;
    }
    const int l = blockIdx.z / 7, m = blockIdx.z % 7;
    const float* srcs[7] = {Wq, Wk, Wv, Wp, Wo, W1, W2};
    const float* src = srcs[m] + (size_t)l * CDIM * CDIM;
    ushort* dst;
    if (m < 3)       dst = Wtqkv + (size_t)l * QKVDIM * CDIM + (size_t)m * CDIM * CDIM;
    else if (m == 3) dst = Wtp + (size_t)l * CDIM * CDIM;
    else if (m == 4) dst = Wto + (size_t)l * CDIM * CDIM;
    else if (m == 5) dst = Wt1 + (size_t)l * CDIM * CDIM;
    else             dst = Wt2 + (size_t)l * CDIM * CDIM;
    __shared__ float tile[32][33];
    const int c0 = blockIdx.x * 32, r0 = blockIdx.y * 32;
    const float4 v = *(const float4*)&src[(size_t)(r0 + ty) * CDIM + c0 + tx * 4];
    tile[tx * 4 + 0][ty] = v.x;
    tile[tx * 4 + 1][ty] = v.y;
    tile[tx * 4 + 2][ty] = v.z;
    tile[tx * 4 + 3][ty] = v.w;
    __syncthreads();
    const float a0 = tile[ty][tx * 4 + 0], a1 = tile[ty][tx * 4 + 1];
    const float a2 = tile[ty][tx * 4 + 2], a3 = tile[ty][tx * 4 + 3];
    uint2 pk;
    pk.x = (unsigned)f2bf(a0) | ((unsigned)f2bf(a1) << 16);
    pk.y = (unsigned)f2bf(a2) | ((unsigned)f2bf(a3) << 16);
    *(uint2*)&dst[(size_t)(c0 + ty) * CDIM + r0 + tx * 4] = pk;
}

// ---------------- LayerNorm: wave-per-row, no LDS/barrier; f32 in (xscale), bf16 out ----
__global__ __launch_bounds__(256) void ln_kernel(const float* __restrict__ in,
                                                 const float* __restrict__ g,
                                                 const float* __restrict__ bta,
                                                 ushort* __restrict__ y, float xscale) {
    const int w = threadIdx.x >> 6, lane = threadIdx.x & 63;
    const int row = blockIdx.x * 4 + w;
    const float* xr = in + (size_t)row * CDIM;
    float4 v0 = *(const float4*)&xr[lane * 4];
    float4 v1 = *(const float4*)&xr[256 + lane * 4];
    float4 v2 = *(const float4*)&xr[512 + lane * 4];
    v0.x *= xscale; v0.y *= xscale; v0.z *= xscale; v0.w *= xscale;
    v1.x *= xscale; v1.y *= xscale; v1.z *= xscale; v1.w *= xscale;
    v2.x *= xscale; v2.y *= xscale; v2.z *= xscale; v2.w *= xscale;
    float s  = v0.x + v0.y + v0.z + v0.w + v1.x + v1.y + v1.z + v1.w
             + v2.x + v2.y + v2.z + v2.w;
    float ss = v0.x * v0.x + v0.y * v0.y + v0.z * v0.z + v0.w * v0.w
             + v1.x * v1.x + v1.y * v1.y + v1.z * v1.z + v1.w * v1.w
             + v2.x * v2.x + v2.y * v2.y + v2.z * v2.z + v2.w * v2.w;
#pragma unroll
    for (int off = 32; off; off >>= 1) {
        s  += __shfl_xor(s, off);
        ss += __shfl_xor(ss, off);
    }
    const float mean = s * (1.f / CDIM);
    const float var  = ss * (1.f / CDIM) - mean * mean;
    const float rstd = rsqrtf(var + 1e-5f);
    ushort* yr = y + (size_t)row * CDIM;
#pragma unroll
    for (int c = 0; c < 3; ++c) {
        const int col = c * 256 + lane * 4;
        const float4 vv = (c == 0) ? v0 : (c == 1) ? v1 : v2;
        const float4 g4 = *(const float4*)&g[col];
        const float4 b4 = *(const float4*)&bta[col];
        ushort o0 = f2bf((vv.x - mean) * rstd * g4.x + b4.x);
        ushort o1 = f2bf((vv.y - mean) * rstd * g4.y + b4.y);
        ushort o2 = f2bf((vv.z - mean) * rstd * g4.z + b4.z);
        ushort o3 = f2bf((vv.w - mean) * rstd * g4.w + b4.w);
        uint2 pk; pk.x = (unsigned)o0 | ((unsigned)o1 << 16);
        pk.y = (unsigned)o2 | ((unsigned)o3 << 16);
        *(uint2*)&yr[col] = pk;
    }
}

// ---------------- MFMA bf16 GEMM: 64x64 tile, BK=64, dbuf, XCD-swizzled, 4 blocks/CU ----
// For the N=768 GEMMs: grid (63,12)=756 blocks -> single occupancy round at high fill.
// Same XOR chunk swizzle + K-ascending MFMA chain as gemm64 -> bit-identical outputs.
// EPI 0: bf16 store; 1: gelu->bf16; 2: Out(f32) = resid*rscale + acc + bias
template <int EPI>
__global__ __launch_bounds__(256, 4) void gemm64x64(const ushort* __restrict__ A,
                                                    const ushort* __restrict__ Bt,
                                                    const float* __restrict__ bias,
                                                    void* Out, int M, int ldo,
                                                    const float* resid, float rscale,
                                                    size_t zsB, size_t zsO) {
    __shared__ ushort lds[16384];              // 2 x 16 KB: [128 rows][64 k]
    const int tid = threadIdx.x;
    const int w = tid >> 6, lane = tid & 63;
    const int nwg = gridDim.x * gridDim.y;
    const int newid = xcd_swz(blockIdx.y * gridDim.x + blockIdx.x, nwg);
    const int col0 = (newid % gridDim.y) * 64;
    const int row0 = (newid / gridDim.y) * 64;
    const size_t zb = blockIdx.z;
    Bt += zb * zsB;
    if (EPI == 2) Out = (void*)((float*)Out + zb * zsO);
    else          Out = (void*)((ushort*)Out + zb * zsO);

    const int srow8  = lane >> 3;
    const int schunk = (lane & 7) ^ srow8;

#define STG44(buf, k0)                                                          \
    {                                                                           \
        _Pragma("unroll")                                                       \
        for (int g = 0; g < 4; ++g) {                                           \
            const int grp = w * 4 + g;                                          \
            const int r = grp * 8 + srow8;                                      \
            const ushort* src = (grp < 8)                                       \
                ? A  + (size_t)(row0 + r) * CDIM + (k0) + schunk * 8            \
                : Bt + (size_t)(col0 + (r - 64)) * CDIM + (k0) + schunk * 8;    \
            gload_lds16(src, (char*)lds + (buf) * 16384 + grp * 1024);          \
        }                                                                       \
    }

    const int wm = w * 16;
    const int lr = lane & 15, q = lane >> 4;
    f32x4 acc[4] = {};

    STG44(0, 0);
    __syncthreads();
    int cur = 0;
    for (int k0 = 0; k0 < CDIM; k0 += 64) {
        if (k0 + 64 < CDIM) STG44(cur ^ 1, k0 + 64);
        const int base = cur * 8192;           // ushort offset (16 KB)
#pragma unroll
        for (int kk = 0; kk < 2; ++kk) {
            const int ra = wm + lr;
            s16x8 af = *(const s16x8*)&lds[base + ra * 64 + ((((kk << 2) | q) ^ (ra & 7)) << 3)];
            s16x8 bfr[4];
#pragma unroll
            for (int j = 0; j < 4; ++j) {
                const int r = 64 + j * 16 + lr;
                bfr[j] = *(const s16x8*)&lds[base + r * 64 + ((((kk << 2) | q) ^ (r & 7)) << 3)];
            }
#pragma unroll
            for (int j = 0; j < 4; ++j)
                acc[j] = __builtin_amdgcn_mfma_f32_16x16x32_bf16(af, bfr[j], acc[j], 0, 0, 0);
        }
        __syncthreads();
        cur ^= 1;
    }
#undef STG44

    const int lrr = (lane >> 4) * 4;
    const int lc = lane & 15;
#pragma unroll
    for (int j = 0; j < 4; ++j) {
        const int col = col0 + j * 16 + lc;
        const float bv = bias ? bias[col] : 0.f;
#pragma unroll
        for (int r = 0; r < 4; ++r) {
            const int row = row0 + wm + lrr + r;
            if (row >= M) continue;
            const float v = acc[j][r] + bv;
            if (EPI == 0)
                ((ushort*)Out)[(size_t)row * ldo + col] = f2bf(v);
            else if (EPI == 1)
                ((ushort*)Out)[(size_t)row * ldo + col] = f2bf(gelu_f(v));
            else {
                float* p = (float*)Out + (size_t)row * ldo + col;
                *p = resid[(size_t)row * ldo + col] * rscale + v;
            }
        }
    }
}

// ---------------- MFMA bf16 GEMM: 128x128 tile, BK=32, dbuf, XCD-swizzled (QKV) --------
template <int EPI>
__global__ __launch_bounds__(256, 3) void gemm128(const ushort* __restrict__ A,
                                                  const ushort* __restrict__ Bt,
                                                  const float* __restrict__ bias,
                                                  void* Out, int M, int ldo) {
    __shared__ ushort lds[16384];              // 2 x 16 KB
    const int tid = threadIdx.x;
    const int w = tid >> 6, lane = tid & 63;
    const int nwg = gridDim.x * gridDim.y;
    const int newid = xcd_swz(blockIdx.y * gridDim.x + blockIdx.x, nwg);
    const int col0 = (newid % gridDim.y) * 128;
    const int row0 = (newid / gridDim.y) * 128;
    const int srow   = lane >> 2;
    const int schunk = (lane & 3) ^ ((lane >> 3) & 3);
    const int wm = (w >> 1) * 64, wn = (w & 1) * 64;
    const int lr = lane & 15, q = lane >> 4;

#define STAGE128(buf, k0)                                                       \
    {                                                                           \
        _Pragma("unroll")                                                       \
        for (int g = 0; g < 4; ++g) {                                           \
            const int sp = w * 4 + g;                                           \
            const int r = sp * 16 + srow;                                       \
            const ushort* src = (r < 128)                                       \
                ? A  + (size_t)(row0 + r) * CDIM + (k0) + schunk * 8            \
                : Bt + (size_t)(col0 + (r - 128)) * CDIM + (k0) + schunk * 8;   \
            gload_lds16(src, (char*)lds + (buf) * 16384 + sp * 1024);           \
        }                                                                       \
    }

    f32x4 acc[4][4] = {};
    STAGE128(0, 0);
    __syncthreads();
    int cur = 0;
    for (int k0 = 0; k0 < CDIM; k0 += 32) {
        if (k0 + 32 < CDIM) STAGE128(cur ^ 1, k0 + 32);
        const int base = cur * 8192;
        s16x8 af[4], bfr[4];
#pragma unroll
        for (int i = 0; i < 4; ++i) {
            const int r = wm + i * 16 + lr;
            af[i] = *(const s16x8*)&lds[base + r * 32 + ((q ^ ((r >> 1) & 3)) << 3)];
        }
#pragma unroll
        for (int j = 0; j < 4; ++j) {
            const int r = 128 + wn + j * 16 + lr;
            bfr[j] = *(const s16x8*)&lds[base + r * 32 + ((q ^ ((r >> 1) & 3)) << 3)];
        }
#pragma unroll
        for (int i = 0; i < 4; ++i)
#pragma unroll
            for (int j = 0; j < 4; ++j)
                acc[i][j] = __builtin_amdgcn_mfma_f32_16x16x32_bf16(af[i], bfr[j], acc[i][j], 0, 0, 0);
        __syncthreads();
        cur ^= 1;
    }
#undef STAGE128

    const int crow0 = row0 + (w >> 1) * 64;
    const int ccol0 = col0 + (w & 1) * 64;
    const int lrr = (lane >> 4) * 4;
    const int lc = lane & 15;
#pragma unroll
    for (int j = 0; j < 4; ++j) {
        const int col = ccol0 + j * 16 + lc;
        const float bv = bias ? bias[col] : 0.f;
#pragma unroll
        for (int i = 0; i < 4; ++i) {
#pragma unroll
            for (int r = 0; r < 4; ++r) {
                const int row = crow0 + i * 16 + lrr + r;
                if (row >= M) continue;
                const float v = acc[i][j][r] + bv;
                if (EPI == 0)
                    ((ushort*)Out)[(size_t)row * ldo + col] = f2bf(v);
                else if (EPI == 1)
                    ((ushort*)Out)[(size_t)row * ldo + col] = f2bf(gelu_f(v));
            }
        }
    }
}

// ---------------- MFMA banded rel-pos attention (verified round-11 structure) ----------
__global__ __launch_bounds__(256, 3) void attn_mfma(
    const ushort* __restrict__ qkv, const ushort* __restrict__ pb,
    const float* __restrict__ pos_u, const float* __restrict__ pos_v,
    ushort* __restrict__ o) {
    __shared__ __align__(16) char smem[51200];
    ushort* Kl   = (ushort*)smem;               // [176][64] swizzled
    ushort* Pl   = (ushort*)smem;               // phase2 [64][200]
    ushort* Vsub = (ushort*)(smem + 25600);     // [2][192][16]
    ushort* Bd   = (ushort*)(smem + 37888);     // [4][16][104]

    const int tid = threadIdx.x;
    const int w = tid >> 6, lane = tid & 63;
    const int t0 = blockIdx.x * 64;
    const int h = blockIdx.y, b = blockIdx.z;
    const int m0 = w * 16;
    const int lr = lane & 15, lk = (lane >> 4) * 8, q = lane >> 4;

    auto vsrc = [&](int sp) -> const ushort* {
        const int ob = sp * 1024 + lane * 16;
        const int d0c = ob / 6144;
        const int rem = ob - d0c * 6144;
        const int j = rem >> 5;
        const int halfo = (rem & 31) >> 4;
        int t = t0 - HALFW + j; t = t < 0 ? 0 : (t < TSEQ ? t : TSEQ - 1);
        return qkv + (size_t)(b * TSEQ + t) * QKVDIM + 2 * CDIM + h * DKK
               + (d0c & 1) * 16 + halfo * 8;
    };

    // ---- Q + pos loads (oldest VMEM) ----
    int tq = t0 + m0 + lr; tq = tq < TSEQ ? tq : TSEQ - 1;
    const ushort* qp = qkv + (size_t)(b * TSEQ + tq) * QKVDIM + h * DKK;
    s16x8 qr0 = *(const s16x8*)(qp + lk);
    s16x8 qr1 = *(const s16x8*)(qp + 32 + lk);
    const float* puB = pos_u + h * DKK;
    const float* pvB = pos_v + h * DKK;
    float puA[16], pvA[16];
    *(float4*)&puA[0]  = *(const float4*)(puB + lk);
    *(float4*)&puA[4]  = *(const float4*)(puB + lk + 4);
    *(float4*)&puA[8]  = *(const float4*)(puB + 32 + lk);
    *(float4*)&puA[12] = *(const float4*)(puB + 32 + lk + 4);
    *(float4*)&pvA[0]  = *(const float4*)(pvB + lk);
    *(float4*)&pvA[4]  = *(const float4*)(pvB + lk + 4);
    *(float4*)&pvA[8]  = *(const float4*)(pvB + 32 + lk);
    *(float4*)&pvA[12] = *(const float4*)(pvB + 32 + lk + 4);

    // ---- V pass-A + K gloads (stay in flight across qu/qv build) ----
#pragma unroll
    for (int g = 0; g < 3; ++g) {
        const int sp = w * 3 + g;
        gload_lds16(vsrc(sp), (char*)Vsub + sp * 1024);
    }
    {
        const int srow8 = lane >> 3;
        const int schunk = (lane & 7) ^ srow8;
#pragma unroll
        for (int g = 0; g < 6; ++g) {
            const int sp = w * 6 + g;
            if (sp < 22) {
                const int r = sp * 8 + srow8;
                int kb = t0 - HALFW + r; kb = kb < 0 ? 0 : (kb < TSEQ ? kb : TSEQ - 1);
                const ushort* src = qkv + (size_t)(b * TSEQ + kb) * QKVDIM + CDIM
                                    + h * DKK + schunk * 8;
                gload_lds16(src, (char*)Kl + sp * 1024);
            }
        }
    }

    // ---- build qu/qv first (frees the 32-reg pos arrays before pfr preload) ----
    s16x8 qu0, qu1, qv0, qv1;
#pragma unroll
    for (int e = 0; e < 8; ++e) {
        const float q0 = bf2f((ushort)qr0[e]), q1 = bf2f((ushort)qr1[e]);
        qu0[e] = (short)f2bf(q0 + puA[e]);
        qu1[e] = (short)f2bf(q1 + puA[8 + e]);
        qv0[e] = (short)f2bf(q0 + pvA[e]);
        qv1[e] = (short)f2bf(q1 + pvA[8 + e]);
    }

    // ---- rel-pos B-fragments straight from global (L2-hot) ----
    const ushort* pbh = pb + (size_t)949 * CDIM + h * DKK;
    s16x8 pfr[7][2];
#pragma unroll
    for (int uf = 0; uf < 7; ++uf) {
        pfr[uf][0] = *(const s16x8*)&pbh[(size_t)(uf * 16 + lr) * CDIM + lk];
        pfr[uf][1] = *(const s16x8*)&pbh[(size_t)(uf * 16 + lr) * CDIM + 32 + lk];
    }
    __syncthreads();

    const f32x4 zero = {0.f, 0.f, 0.f, 0.f};
    f32x4 acS[11], acB[7];
    __builtin_amdgcn_s_setprio(1);
#pragma unroll
    for (int uf = 0; uf < 7; ++uf) {
        acB[uf] = __builtin_amdgcn_mfma_f32_16x16x32_bf16(qv0, pfr[uf][0], zero, 0, 0, 0);
        acB[uf] = __builtin_amdgcn_mfma_f32_16x16x32_bf16(qv1, pfr[uf][1], acB[uf], 0, 0, 0);
    }
#pragma unroll
    for (int jf = 0; jf < 11; ++jf) {
        const int rr = jf * 16 + lr;
        const int sw = rr & 7;
        s16x8 k0 = *(const s16x8*)&Kl[rr * 64 + (((q)     ^ sw) << 3)];
        s16x8 k1 = *(const s16x8*)&Kl[rr * 64 + (((q | 4) ^ sw) << 3)];
        acS[jf] = __builtin_amdgcn_mfma_f32_16x16x32_bf16(qu0, k0, zero, 0, 0, 0);
        acS[jf] = __builtin_amdgcn_mfma_f32_16x16x32_bf16(qu1, k1, acS[jf], 0, 0, 0);
    }
    __builtin_amdgcn_s_setprio(0);

    ushort* bdw = Bd + w * 16 * 104;
#pragma unroll
    for (int uf = 0; uf < 7; ++uf)
#pragma unroll
        for (int r = 0; r < 4; ++r)
            bdw[((lane >> 4) * 4 + r) * 104 + uf * 16 + lr] = f2bf(acB[uf][r]);
    float mx[4] = {-1e30f, -1e30f, -1e30f, -1e30f};
#pragma unroll
    for (int jf = 0; jf < 11; ++jf)
#pragma unroll
        for (int r = 0; r < 4; ++r) {
            const int tl = (lane >> 4) * 4 + r;
            const int tloc = m0 + tl;
            const int j = jf * 16 + lr;
            const int u = j - tloc;
            const int s = t0 - HALFW + j;
            const bool valid = (u >= 0) & (u <= 2 * HALFW) & (s >= 0) & (s < TSEQ)
                               & (t0 + tloc < TSEQ);
            float sc = -1e30f;
            if (valid) sc = (acS[jf][r] + bf2f(bdw[tl * 104 + u])) * 0.125f;
            acS[jf][r] = sc;
            mx[r] = fmaxf(mx[r], sc);
        }
#pragma unroll
    for (int r = 0; r < 4; ++r)
#pragma unroll
        for (int off = 8; off; off >>= 1)
            mx[r] = fmaxf(mx[r], __shfl_xor(mx[r], off));
    float sm[4] = {0.f, 0.f, 0.f, 0.f};
#pragma unroll
    for (int jf = 0; jf < 11; ++jf)
#pragma unroll
        for (int r = 0; r < 4; ++r) {
            float e = __expf(acS[jf][r] - mx[r]);
            acS[jf][r] = e;
            sm[r] += e;
        }
#pragma unroll
    for (int r = 0; r < 4; ++r) {
#pragma unroll
        for (int off = 8; off; off >>= 1) sm[r] += __shfl_xor(sm[r], off);
        sm[r] = 1.f / sm[r];
    }
    __syncthreads();

    s16x8 vr0 = *vsrc(12 + w * 3 + 0);
    s16x8 vr1 = *vsrc(12 + w * 3 + 1);
    s16x8 vr2 = *vsrc(12 + w * 3 + 2);

#pragma unroll
    for (int jf = 0; jf < 11; ++jf)
#pragma unroll
        for (int r = 0; r < 4; ++r)
            Pl[(m0 + (lane >> 4) * 4 + r) * 200 + jf * 16 + lr] = f2bf(acS[jf][r]);
#pragma unroll
    for (int r = 0; r < 4; ++r)
        Pl[(m0 + (lane >> 4) * 4 + r) * 200 + 176 + lr] = 0;

    s16x8 pa[6];
#pragma unroll
    for (int ks = 0; ks < 6; ++ks)
        pa[ks] = *(const s16x8*)&Pl[(m0 + lr) * 200 + ks * 32 + lk];

    const unsigned vbase = LDSOFF(Vsub);
#pragma unroll
    for (int nf = 0; nf < 2; ++nf) {
        const unsigned abase = vbase + (nf & 1) * 6144 + ((lane >> 4) << 8) + ((lane & 15) << 1);
        s16x4 lo[6], hi[6];
#pragma unroll
        for (int ks = 0; ks < 6; ++ks) {
            lo[ks] = tr_read(abase + ks * 1024);
            hi[ks] = tr_read128(abase + ks * 1024);
        }
        asm volatile("s_waitcnt lgkmcnt(0)" ::: "memory");
        __builtin_amdgcn_sched_barrier(0);
        f32x4 acO = {};
        __builtin_amdgcn_s_setprio(1);
#pragma unroll
        for (int ks = 0; ks < 6; ++ks) {
            s16x8 vb = __builtin_shufflevector(lo[ks], hi[ks], 0, 1, 2, 3, 4, 5, 6, 7);
            acO = __builtin_amdgcn_mfma_f32_16x16x32_bf16(pa[ks], vb, acO, 0, 0, 0);
        }
        __builtin_amdgcn_s_setprio(0);
#pragma unroll
        for (int r = 0; r < 4; ++r) {
            const int t = t0 + m0 + (lane >> 4) * 4 + r;
            if (t < TSEQ)
                o[(size_t)(b * TSEQ + t) * CDIM + h * DKK + nf * 16 + lr] =
                    f2bf(acO[r] * sm[r]);
        }
    }
    __syncthreads();

    *(s16x8*)((char*)Vsub + (w * 3 + 0) * 1024 + lane * 16) = vr0;
    *(s16x8*)((char*)Vsub + (w * 3 + 1) * 1024 + lane * 16) = vr1;
    *(s16x8*)((char*)Vsub + (w * 3 + 2) * 1024 + lane * 16) = vr2;
    __syncthreads();

#pragma unroll
    for (int nf = 2; nf < 4; ++nf) {
        const unsigned abase = vbase + (nf & 1) * 6144 + ((lane >> 4) << 8) + ((lane & 15) << 1);
        s16x4 lo[6], hi[6];
#pragma unroll
        for (int ks = 0; ks < 6; ++ks) {
            lo[ks] = tr_read(abase + ks * 1024);
            hi[ks] = tr_read128(abase + ks * 1024);
        }
        asm volatile("s_waitcnt lgkmcnt(0)" ::: "memory");
        __builtin_amdgcn_sched_barrier(0);
        f32x4 acO = {};
        __builtin_amdgcn_s_setprio(1);
#pragma unroll
        for (int ks = 0; ks < 6; ++ks) {
            s16x8 vb = __builtin_shufflevector(lo[ks], hi[ks], 0, 1, 2, 3, 4, 5, 6, 7);
            acO = __builtin_amdgcn_mfma_f32_16x16x32_bf16(pa[ks], vb, acO, 0, 0, 0);
        }
        __builtin_amdgcn_s_setprio(0);
#pragma unroll
        for (int r = 0; r < 4; ++r) {
            const int t = t0 + m0 + (lane >> 4) * 4 + r;
            if (t < TSEQ)
                o[(size_t)(b * TSEQ + t) * CDIM + h * DKK + nf * 16 + lr] =
                    f2bf(acO[r] * sm[r]);
        }
    }
}

// ---------------- launch ----------------
extern "C" void kernel_launch(void* const* d_in, const int* in_sizes, int n_in,
                              void* d_out, int out_size, void* d_ws, size_t ws_size,
                              hipStream_t stream) {
    const float* x     = (const float*)d_in[0];
    const float* Wq    = (const float*)d_in[1];
    const float* bq    = (const float*)d_in[2];
    const float* Wk    = (const float*)d_in[3];
    const float* bk    = (const float*)d_in[4];
    const float* Wv    = (const float*)d_in[5];
    const float* bv    = (const float*)d_in[6];
    const float* Wo    = (const float*)d_in[7];
    const float* bo    = (const float*)d_in[8];
    const float* Wp    = (const float*)d_in[9];
    const float* pos_u = (const float*)d_in[10];
    const float* pos_v = (const float*)d_in[11];
    const float* ln1g  = (const float*)d_in[12];
    const float* ln1b  = (const float*)d_in[13];
    const float* ln2g  = (const float*)d_in[14];
    const float* ln2b  = (const float*)d_in[15];
    const float* W1    = (const float*)d_in[16];
    const float* b1    = (const float*)d_in[17];
    const float* W2    = (const float*)d_in[18];
    const float* b2    = (const float*)d_in[19];

    float* h = (float*)d_out;
    const float XS = 27.712812921102035f;   // sqrt(768)

    char* p = (char*)d_ws;
    ushort* Wtqkv = (ushort*)p;               p += (size_t)LNUM * QKVDIM * CDIM * 2;
    ushort* Wtp   = (ushort*)p;               p += (size_t)LNUM * CDIM * CDIM * 2;
    ushort* Wto   = (ushort*)p;               p += (size_t)LNUM * CDIM * CDIM * 2;
    ushort* Wt1   = (ushort*)p;               p += (size_t)LNUM * CDIM * CDIM * 2;
    ushort* Wt2   = (ushort*)p;               p += (size_t)LNUM * CDIM * CDIM * 2;
    float*  bqkv  = (float*)p;                p += (size_t)LNUM * QKVDIM * 4;
    ushort* pe    = (ushort*)p;               p += (size_t)2048 * CDIM * 2;
    ushort* pb    = (ushort*)p;               p += (size_t)LNUM * 2048 * CDIM * 2;
    ushort* y     = (ushort*)p;               p += (size_t)MPAD * CDIM * 2;
    ushort* qkv   = (ushort*)p;               p += (size_t)MPAD * QKVDIM * 2;
    ushort* o     = (ushort*)p;               p += (size_t)MPAD * CDIM * 2;
    ushort* hid   = (ushort*)p;               p += (size_t)MPAD * CDIM * 2;

    transpose_pack<<<dim3(24, 24, 15), dim3(8, 32), 0, stream>>>(
        Wq, Wk, Wv, Wp, Wo, W1, W2, Wtqkv, Wtp, Wto, Wt1, Wt2,
        pe, bq, bk, bv, bqkv);

    const int MB = (MROWS + 63) / 64;        // 63 row-blocks
    const dim3 gQKV(32, QKVDIM / 128);       // 128x128 tiles: (32, 18) = 576 blocks
    const dim3 gC(MB, CDIM / 64);            // 64x64 tiles: (63, 12) = 756 blocks
    const dim3 gP(4, CDIM / 64, LNUM);       // (4, 12, 2)
    const dim3 gA(16, HHEADS, BBATCH);

    gemm64x64<0><<<gP, 256, 0, stream>>>(pe + (size_t)896 * CDIM, Wtp, nullptr,
                                         pb + (size_t)896 * CDIM, 256, CDIM,
                                         nullptr, 0.f,
                                         (size_t)CDIM * CDIM, (size_t)2048 * CDIM);

    for (int l = 0; l < LNUM; ++l) {
        const size_t wo = (size_t)l * CDIM * CDIM;
        const float* res1 = (l == 0) ? x : h;
        const float rs1   = (l == 0) ? XS : 1.f;
        ln_kernel<<<MROWS / 4, 256, 0, stream>>>(res1, ln1g + l * CDIM, ln1b + l * CDIM, y, rs1);
        gemm128<0><<<gQKV, 256, 0, stream>>>(y, Wtqkv + (size_t)l * QKVDIM * CDIM,
                                             bqkv + l * QKVDIM, qkv, MROWS, QKVDIM);
        attn_mfma<<<gA, 256, 0, stream>>>(
            qkv, pb + (size_t)l * 2048 * CDIM,
            pos_u + l * HHEADS * DKK, pos_v + l * HHEADS * DKK, o);
        gemm64x64<2><<<gC, 256, 0, stream>>>(o, Wto + wo, bo + l * CDIM, h, MROWS, CDIM,
                                             res1, rs1, 0, 0);
        ln_kernel<<<MROWS / 4, 256, 0, stream>>>(h, ln2g + l * CDIM, ln2b + l * CDIM, y, 1.f);
        gemm64x64<1><<<gC, 256, 0, stream>>>(y, Wt1 + wo, b1 + l * CDIM, hid, MROWS, CDIM,
                                             nullptr, 0.f, 0, 0);
        gemm64x64<2><<<gC, 256, 0, stream>>>(hid, Wt2 + wo, b2 + l * CDIM, h, MROWS, CDIM,
                                             h, 1.f, 0, 0);
    }
}

// Round 16
// 217.704 us; speedup vs baseline: 1.5955x; 1.0002x over previous
//
#include <hip/hip_runtime.h>
#include <math.h>

#define LNUM 2
#define BBATCH 4
#define TSEQ 1000
#define CDIM 768
#define HHEADS 12
#define DKK 64
#define PPOS (2*TSEQ-1)   // 1999
#define HALFW 50
#define MROWS (BBATCH*TSEQ)     // 4000
#define MPAD 4096
#define QKVDIM (3*CDIM)         // 2304
#define NS 176                  // real key span per 64-query tile (padded to 192)

typedef __attribute__((ext_vector_type(8))) short s16x8;
typedef __attribute__((ext_vector_type(4))) short s16x4;
typedef __attribute__((ext_vector_type(4))) float f32x4;

#define LDSOFF(p) ((unsigned)(uintptr_t)(__attribute__((address_space(3))) const void*)(p))

__device__ __forceinline__ ushort f2bf(float x) {
    unsigned u = __float_as_uint(x);
    unsigned r = u + 0x7FFFu + ((u >> 16) & 1u);
    return (ushort)(r >> 16);
}
__device__ __forceinline__ float bf2f(ushort h) {
    return __uint_as_float(((unsigned)h) << 16);
}
__device__ __forceinline__ float gelu_f(float x) {
    float u = 0.7978845608028654f * (x + 0.044715f * x * x * x);
    return 0.5f * x * (1.f + tanhf(u));
}
__device__ __forceinline__ void gload_lds16(const void* g, void* l) {
    __builtin_amdgcn_global_load_lds(
        (const __attribute__((address_space(1))) void*)g,
        (__attribute__((address_space(3))) void*)l, 16, 0, 0);
}
__device__ __forceinline__ s16x4 tr_read(unsigned addr) {
    s16x4 d;
    asm volatile("ds_read_b64_tr_b16 %0, %1" : "=v"(d) : "v"(addr));
    return d;
}
__device__ __forceinline__ s16x4 tr_read128(unsigned addr) {
    s16x4 d;
    asm volatile("ds_read_b64_tr_b16 %0, %1 offset:128" : "=v"(d) : "v"(addr));
    return d;
}
// bijective XCD-chunked swizzle (m204): contiguous tile chunk per XCD
__device__ __forceinline__ int xcd_swz(int orig, int nwg) {
    const int xcd = orig & 7, ixc = orig >> 3;
    const int qq = nwg >> 3, rr = nwg & 7;
    return (xcd < rr ? xcd * (qq + 1) : rr * (qq + 1) + (xcd - rr) * qq) + ixc;
}

// ---------------- weight transpose + bf16 convert, fused with small prep ----------------
// z 0..13: weight slice l*7+m; z==14: pos-enc rows [896,1152) + qkv bias pack.
__global__ __launch_bounds__(256) void transpose_pack(
    const float* __restrict__ Wq, const float* __restrict__ Wk,
    const float* __restrict__ Wv, const float* __restrict__ Wp,
    const float* __restrict__ Wo, const float* __restrict__ W1,
    const float* __restrict__ W2,
    ushort* __restrict__ Wtqkv, ushort* __restrict__ Wtp,
    ushort* __restrict__ Wto, ushort* __restrict__ Wt1, ushort* __restrict__ Wt2,
    ushort* __restrict__ pe,
    const float* __restrict__ bq, const float* __restrict__ bk,
    const float* __restrict__ bv, float* __restrict__ bqkv) {
    const int tx = threadIdx.x, ty = threadIdx.y;       // (8, 32)
    if (blockIdx.z == 14) {
        const int linear = blockIdx.y * 24 + blockIdx.x;
        const int idx = linear * 256 + ty * 8 + tx;
        const int npair = 256 * (CDIM / 2);
        if (idx < npair) {
            int jloc = idx / (CDIM / 2);
            int m = idx - jloc * (CDIM / 2);
            int j = 896 + jloc;
            float rel = (float)(TSEQ - 1 - j);
            float div = expf(-(float)(2 * m) * (9.210340371976184f / (float)CDIM));
            float a = rel * div;
            pe[(size_t)j * CDIM + 2 * m]     = f2bf(sinf(a));
            pe[(size_t)j * CDIM + 2 * m + 1] = f2bf(cosf(a));
        }
        if (idx < LNUM * QKVDIM) {
            int l = idx / QKVDIM, c = idx - l * QKVDIM;
            float v;
            if (c < CDIM)            v = bq[l * CDIM + c];
            else if (c < 2 * CDIM)   v = bk[l * CDIM + c - CDIM];
            else                     v = bv[l * CDIM + c - 2 * CDIM];
            bqkv[idx] = v;
        }
        return;
    }
    const int l = blockIdx.z / 7, m = blockIdx.z % 7;
    const float* srcs[7] = {Wq, Wk, Wv, Wp, Wo, W1, W2};
    const float* src = srcs[m] + (size_t)l * CDIM * CDIM;
    ushort* dst;
    if (m < 3)       dst = Wtqkv + (size_t)l * QKVDIM * CDIM + (size_t)m * CDIM * CDIM;
    else if (m == 3) dst = Wtp + (size_t)l * CDIM * CDIM;
    else if (m == 4) dst = Wto + (size_t)l * CDIM * CDIM;
    else if (m == 5) dst = Wt1 + (size_t)l * CDIM * CDIM;
    else             dst = Wt2 + (size_t)l * CDIM * CDIM;
    __shared__ float tile[32][33];
    const int c0 = blockIdx.x * 32, r0 = blockIdx.y * 32;
    const float4 v = *(const float4*)&src[(size_t)(r0 + ty) * CDIM + c0 + tx * 4];
    tile[tx * 4 + 0][ty] = v.x;
    tile[tx * 4 + 1][ty] = v.y;
    tile[tx * 4 + 2][ty] = v.z;
    tile[tx * 4 + 3][ty] = v.w;
    __syncthreads();
    const float a0 = tile[ty][tx * 4 + 0], a1 = tile[ty][tx * 4 + 1];
    const float a2 = tile[ty][tx * 4 + 2], a3 = tile[ty][tx * 4 + 3];
    uint2 pk;
    pk.x = (unsigned)f2bf(a0) | ((unsigned)f2bf(a1) << 16);
    pk.y = (unsigned)f2bf(a2) | ((unsigned)f2bf(a3) << 16);
    *(uint2*)&dst[(size_t)(c0 + ty) * CDIM + r0 + tx * 4] = pk;
}

// ---------------- LayerNorm: wave-per-row, no LDS/barrier; f32 in (xscale), bf16 out ----
__global__ __launch_bounds__(256) void ln_kernel(const float* __restrict__ in,
                                                 const float* __restrict__ g,
                                                 const float* __restrict__ bta,
                                                 ushort* __restrict__ y, float xscale) {
    const int w = threadIdx.x >> 6, lane = threadIdx.x & 63;
    const int row = blockIdx.x * 4 + w;
    const float* xr = in + (size_t)row * CDIM;
    float4 v0 = *(const float4*)&xr[lane * 4];
    float4 v1 = *(const float4*)&xr[256 + lane * 4];
    float4 v2 = *(const float4*)&xr[512 + lane * 4];
    v0.x *= xscale; v0.y *= xscale; v0.z *= xscale; v0.w *= xscale;
    v1.x *= xscale; v1.y *= xscale; v1.z *= xscale; v1.w *= xscale;
    v2.x *= xscale; v2.y *= xscale; v2.z *= xscale; v2.w *= xscale;
    float s  = v0.x + v0.y + v0.z + v0.w + v1.x + v1.y + v1.z + v1.w
             + v2.x + v2.y + v2.z + v2.w;
    float ss = v0.x * v0.x + v0.y * v0.y + v0.z * v0.z + v0.w * v0.w
             + v1.x * v1.x + v1.y * v1.y + v1.z * v1.z + v1.w * v1.w
             + v2.x * v2.x + v2.y * v2.y + v2.z * v2.z + v2.w * v2.w;
#pragma unroll
    for (int off = 32; off; off >>= 1) {
        s  += __shfl_xor(s, off);
        ss += __shfl_xor(ss, off);
    }
    const float mean = s * (1.f / CDIM);
    const float var  = ss * (1.f / CDIM) - mean * mean;
    const float rstd = rsqrtf(var + 1e-5f);
    ushort* yr = y + (size_t)row * CDIM;
#pragma unroll
    for (int c = 0; c < 3; ++c) {
        const int col = c * 256 + lane * 4;
        const float4 vv = (c == 0) ? v0 : (c == 1) ? v1 : v2;
        const float4 g4 = *(const float4*)&g[col];
        const float4 b4 = *(const float4*)&bta[col];
        ushort o0 = f2bf((vv.x - mean) * rstd * g4.x + b4.x);
        ushort o1 = f2bf((vv.y - mean) * rstd * g4.y + b4.y);
        ushort o2 = f2bf((vv.z - mean) * rstd * g4.z + b4.z);
        ushort o3 = f2bf((vv.w - mean) * rstd * g4.w + b4.w);
        uint2 pk; pk.x = (unsigned)o0 | ((unsigned)o1 << 16);
        pk.y = (unsigned)o2 | ((unsigned)o3 << 16);
        *(uint2*)&yr[col] = pk;
    }
}

// ---------------- MFMA bf16 GEMM: 64x64 tile, BK=64, dbuf, XCD-swizzled, 5 blocks/CU ----
template <int EPI>
__global__ __launch_bounds__(256, 5) void gemm64x64(const ushort* __restrict__ A,
                                                    const ushort* __restrict__ Bt,
                                                    const float* __restrict__ bias,
                                                    void* Out, int M, int ldo,
                                                    const float* resid, float rscale,
                                                    size_t zsB, size_t zsO) {
    __shared__ ushort lds[16384];              // 2 x 16 KB: [128 rows][64 k]
    const int tid = threadIdx.x;
    const int w = tid >> 6, lane = tid & 63;
    const int nwg = gridDim.x * gridDim.y;
    const int newid = xcd_swz(blockIdx.y * gridDim.x + blockIdx.x, nwg);
    const int col0 = (newid % gridDim.y) * 64;
    const int row0 = (newid / gridDim.y) * 64;
    const size_t zb = blockIdx.z;
    Bt += zb * zsB;
    if (EPI == 2) Out = (void*)((float*)Out + zb * zsO);
    else          Out = (void*)((ushort*)Out + zb * zsO);

    const int srow8  = lane >> 3;
    const int schunk = (lane & 7) ^ srow8;

#define STG44(buf, k0)                                                          \
    {                                                                           \
        _Pragma("unroll")                                                       \
        for (int g = 0; g < 4; ++g) {                                           \
            const int grp = w * 4 + g;                                          \
            const int r = grp * 8 + srow8;                                      \
            const ushort* src = (grp < 8)                                       \
                ? A  + (size_t)(row0 + r) * CDIM + (k0) + schunk * 8            \
                : Bt + (size_t)(col0 + (r - 64)) * CDIM + (k0) + schunk * 8;    \
            gload_lds16(src, (char*)lds + (buf) * 16384 + grp * 1024);          \
        }                                                                       \
    }

    const int wm = w * 16;
    const int lr = lane & 15, q = lane >> 4;
    f32x4 acc[4] = {};

    STG44(0, 0);
    __syncthreads();
    int cur = 0;
    for (int k0 = 0; k0 < CDIM; k0 += 64) {
        if (k0 + 64 < CDIM) STG44(cur ^ 1, k0 + 64);
        const int base = cur * 8192;           // ushort offset (16 KB)
#pragma unroll
        for (int kk = 0; kk < 2; ++kk) {
            const int ra = wm + lr;
            s16x8 af = *(const s16x8*)&lds[base + ra * 64 + ((((kk << 2) | q) ^ (ra & 7)) << 3)];
            s16x8 bfr[4];
#pragma unroll
            for (int j = 0; j < 4; ++j) {
                const int r = 64 + j * 16 + lr;
                bfr[j] = *(const s16x8*)&lds[base + r * 64 + ((((kk << 2) | q) ^ (r & 7)) << 3)];
            }
#pragma unroll
            for (int j = 0; j < 4; ++j)
                acc[j] = __builtin_amdgcn_mfma_f32_16x16x32_bf16(af, bfr[j], acc[j], 0, 0, 0);
        }
        __syncthreads();
        cur ^= 1;
    }
#undef STG44

    const int lrr = (lane >> 4) * 4;
    const int lc = lane & 15;
#pragma unroll
    for (int j = 0; j < 4; ++j) {
        const int col = col0 + j * 16 + lc;
        const float bv = bias ? bias[col] : 0.f;
#pragma unroll
        for (int r = 0; r < 4; ++r) {
            const int row = row0 + wm + lrr + r;
            if (row >= M) continue;
            const float v = acc[j][r] + bv;
            if (EPI == 0)
                ((ushort*)Out)[(size_t)row * ldo + col] = f2bf(v);
            else if (EPI == 1)
                ((ushort*)Out)[(size_t)row * ldo + col] = f2bf(gelu_f(v));
            else {
                float* p = (float*)Out + (size_t)row * ldo + col;
                *p = resid[(size_t)row * ldo + col] * rscale + v;
            }
        }
    }
}

// ---------------- MFMA bf16 GEMM: 128x128 tile, BK=32, dbuf, XCD-swizzled, 4 blocks/CU -
template <int EPI>
__global__ __launch_bounds__(256, 4) void gemm128(const ushort* __restrict__ A,
                                                  const ushort* __restrict__ Bt,
                                                  const float* __restrict__ bias,
                                                  void* Out, int M, int ldo) {
    __shared__ ushort lds[16384];              // 2 x 16 KB
    const int tid = threadIdx.x;
    const int w = tid >> 6, lane = tid & 63;
    const int nwg = gridDim.x * gridDim.y;
    const int newid = xcd_swz(blockIdx.y * gridDim.x + blockIdx.x, nwg);
    const int col0 = (newid % gridDim.y) * 128;
    const int row0 = (newid / gridDim.y) * 128;
    const int srow   = lane >> 2;
    const int schunk = (lane & 3) ^ ((lane >> 3) & 3);
    const int wm = (w >> 1) * 64, wn = (w & 1) * 64;
    const int lr = lane & 15, q = lane >> 4;

#define STAGE128(buf, k0)                                                       \
    {                                                                           \
        _Pragma("unroll")                                                       \
        for (int g = 0; g < 4; ++g) {                                           \
            const int sp = w * 4 + g;                                           \
            const int r = sp * 16 + srow;                                       \
            const ushort* src = (r < 128)                                       \
                ? A  + (size_t)(row0 + r) * CDIM + (k0) + schunk * 8            \
                : Bt + (size_t)(col0 + (r - 128)) * CDIM + (k0) + schunk * 8;   \
            gload_lds16(src, (char*)lds + (buf) * 16384 + sp * 1024);           \
        }                                                                       \
    }

    f32x4 acc[4][4] = {};
    STAGE128(0, 0);
    __syncthreads();
    int cur = 0;
    for (int k0 = 0; k0 < CDIM; k0 += 32) {
        if (k0 + 32 < CDIM) STAGE128(cur ^ 1, k0 + 32);
        const int base = cur * 8192;
        s16x8 af[4], bfr[4];
#pragma unroll
        for (int i = 0; i < 4; ++i) {
            const int r = wm + i * 16 + lr;
            af[i] = *(const s16x8*)&lds[base + r * 32 + ((q ^ ((r >> 1) & 3)) << 3)];
        }
#pragma unroll
        for (int j = 0; j < 4; ++j) {
            const int r = 128 + wn + j * 16 + lr;
            bfr[j] = *(const s16x8*)&lds[base + r * 32 + ((q ^ ((r >> 1) & 3)) << 3)];
        }
#pragma unroll
        for (int i = 0; i < 4; ++i)
#pragma unroll
            for (int j = 0; j < 4; ++j)
                acc[i][j] = __builtin_amdgcn_mfma_f32_16x16x32_bf16(af[i], bfr[j], acc[i][j], 0, 0, 0);
        __syncthreads();
        cur ^= 1;
    }
#undef STAGE128

    const int crow0 = row0 + (w >> 1) * 64;
    const int ccol0 = col0 + (w & 1) * 64;
    const int lrr = (lane >> 4) * 4;
    const int lc = lane & 15;
#pragma unroll
    for (int j = 0; j < 4; ++j) {
        const int col = ccol0 + j * 16 + lc;
        const float bv = bias ? bias[col] : 0.f;
#pragma unroll
        for (int i = 0; i < 4; ++i) {
#pragma unroll
            for (int r = 0; r < 4; ++r) {
                const int row = crow0 + i * 16 + lrr + r;
                if (row >= M) continue;
                const float v = acc[i][j][r] + bv;
                if (EPI == 0)
                    ((ushort*)Out)[(size_t)row * ldo + col] = f2bf(v);
                else if (EPI == 1)
                    ((ushort*)Out)[(size_t)row * ldo + col] = f2bf(gelu_f(v));
            }
        }
    }
}

// ---------------- MFMA banded rel-pos attention (verified round-11 structure) ----------
__global__ __launch_bounds__(256, 3) void attn_mfma(
    const ushort* __restrict__ qkv, const ushort* __restrict__ pb,
    const float* __restrict__ pos_u, const float* __restrict__ pos_v,
    ushort* __restrict__ o) {
    __shared__ __align__(16) char smem[51200];
    ushort* Kl   = (ushort*)smem;               // [176][64] swizzled
    ushort* Pl   = (ushort*)smem;               // phase2 [64][200]
    ushort* Vsub = (ushort*)(smem + 25600);     // [2][192][16]
    ushort* Bd   = (ushort*)(smem + 37888);     // [4][16][104]

    const int tid = threadIdx.x;
    const int w = tid >> 6, lane = tid & 63;
    const int t0 = blockIdx.x * 64;
    const int h = blockIdx.y, b = blockIdx.z;
    const int m0 = w * 16;
    const int lr = lane & 15, lk = (lane >> 4) * 8, q = lane >> 4;

    auto vsrc = [&](int sp) -> const ushort* {
        const int ob = sp * 1024 + lane * 16;
        const int d0c = ob / 6144;
        const int rem = ob - d0c * 6144;
        const int j = rem >> 5;
        const int halfo = (rem & 31) >> 4;
        int t = t0 - HALFW + j; t = t < 0 ? 0 : (t < TSEQ ? t : TSEQ - 1);
        return qkv + (size_t)(b * TSEQ + t) * QKVDIM + 2 * CDIM + h * DKK
               + (d0c & 1) * 16 + halfo * 8;
    };

    // ---- Q + pos loads (oldest VMEM) ----
    int tq = t0 + m0 + lr; tq = tq < TSEQ ? tq : TSEQ - 1;
    const ushort* qp = qkv + (size_t)(b * TSEQ + tq) * QKVDIM + h * DKK;
    s16x8 qr0 = *(const s16x8*)(qp + lk);
    s16x8 qr1 = *(const s16x8*)(qp + 32 + lk);
    const float* puB = pos_u + h * DKK;
    const float* pvB = pos_v + h * DKK;
    float puA[16], pvA[16];
    *(float4*)&puA[0]  = *(const float4*)(puB + lk);
    *(float4*)&puA[4]  = *(const float4*)(puB + lk + 4);
    *(float4*)&puA[8]  = *(const float4*)(puB + 32 + lk);
    *(float4*)&puA[12] = *(const float4*)(puB + 32 + lk + 4);
    *(float4*)&pvA[0]  = *(const float4*)(pvB + lk);
    *(float4*)&pvA[4]  = *(const float4*)(pvB + lk + 4);
    *(float4*)&pvA[8]  = *(const float4*)(pvB + 32 + lk);
    *(float4*)&pvA[12] = *(const float4*)(pvB + 32 + lk + 4);

    // ---- V pass-A + K gloads (stay in flight across qu/qv build) ----
#pragma unroll
    for (int g = 0; g < 3; ++g) {
        const int sp = w * 3 + g;
        gload_lds16(vsrc(sp), (char*)Vsub + sp * 1024);
    }
    {
        const int srow8 = lane >> 3;
        const int schunk = (lane & 7) ^ srow8;
#pragma unroll
        for (int g = 0; g < 6; ++g) {
            const int sp = w * 6 + g;
            if (sp < 22) {
                const int r = sp * 8 + srow8;
                int kb = t0 - HALFW + r; kb = kb < 0 ? 0 : (kb < TSEQ ? kb : TSEQ - 1);
                const ushort* src = qkv + (size_t)(b * TSEQ + kb) * QKVDIM + CDIM
                                    + h * DKK + schunk * 8;
                gload_lds16(src, (char*)Kl + sp * 1024);
            }
        }
    }

    // ---- build qu/qv first (frees the 32-reg pos arrays before pfr preload) ----
    s16x8 qu0, qu1, qv0, qv1;
#pragma unroll
    for (int e = 0; e < 8; ++e) {
        const float q0 = bf2f((ushort)qr0[e]), q1 = bf2f((ushort)qr1[e]);
        qu0[e] = (short)f2bf(q0 + puA[e]);
        qu1[e] = (short)f2bf(q1 + puA[8 + e]);
        qv0[e] = (short)f2bf(q0 + pvA[e]);
        qv1[e] = (short)f2bf(q1 + pvA[8 + e]);
    }

    // ---- rel-pos B-fragments straight from global (L2-hot) ----
    const ushort* pbh = pb + (size_t)949 * CDIM + h * DKK;
    s16x8 pfr[7][2];
#pragma unroll
    for (int uf = 0; uf < 7; ++uf) {
        pfr[uf][0] = *(const s16x8*)&pbh[(size_t)(uf * 16 + lr) * CDIM + lk];
        pfr[uf][1] = *(const s16x8*)&pbh[(size_t)(uf * 16 + lr) * CDIM + 32 + lk];
    }
    __syncthreads();

    const f32x4 zero = {0.f, 0.f, 0.f, 0.f};
    f32x4 acS[11], acB[7];
    __builtin_amdgcn_s_setprio(1);
#pragma unroll
    for (int uf = 0; uf < 7; ++uf) {
        acB[uf] = __builtin_amdgcn_mfma_f32_16x16x32_bf16(qv0, pfr[uf][0], zero, 0, 0, 0);
        acB[uf] = __builtin_amdgcn_mfma_f32_16x16x32_bf16(qv1, pfr[uf][1], acB[uf], 0, 0, 0);
    }
#pragma unroll
    for (int jf = 0; jf < 11; ++jf) {
        const int rr = jf * 16 + lr;
        const int sw = rr & 7;
        s16x8 k0 = *(const s16x8*)&Kl[rr * 64 + (((q)     ^ sw) << 3)];
        s16x8 k1 = *(const s16x8*)&Kl[rr * 64 + (((q | 4) ^ sw) << 3)];
        acS[jf] = __builtin_amdgcn_mfma_f32_16x16x32_bf16(qu0, k0, zero, 0, 0, 0);
        acS[jf] = __builtin_amdgcn_mfma_f32_16x16x32_bf16(qu1, k1, acS[jf], 0, 0, 0);
    }
    __builtin_amdgcn_s_setprio(0);

    ushort* bdw = Bd + w * 16 * 104;
#pragma unroll
    for (int uf = 0; uf < 7; ++uf)
#pragma unroll
        for (int r = 0; r < 4; ++r)
            bdw[((lane >> 4) * 4 + r) * 104 + uf * 16 + lr] = f2bf(acB[uf][r]);
    float mx[4] = {-1e30f, -1e30f, -1e30f, -1e30f};
#pragma unroll
    for (int jf = 0; jf < 11; ++jf)
#pragma unroll
        for (int r = 0; r < 4; ++r) {
            const int tl = (lane >> 4) * 4 + r;
            const int tloc = m0 + tl;
            const int j = jf * 16 + lr;
            const int u = j - tloc;
            const int s = t0 - HALFW + j;
            const bool valid = (u >= 0) & (u <= 2 * HALFW) & (s >= 0) & (s < TSEQ)
                               & (t0 + tloc < TSEQ);
            float sc = -1e30f;
            if (valid) sc = (acS[jf][r] + bf2f(bdw[tl * 104 + u])) * 0.125f;
            acS[jf][r] = sc;
            mx[r] = fmaxf(mx[r], sc);
        }
#pragma unroll
    for (int r = 0; r < 4; ++r)
#pragma unroll
        for (int off = 8; off; off >>= 1)
            mx[r] = fmaxf(mx[r], __shfl_xor(mx[r], off));
    float sm[4] = {0.f, 0.f, 0.f, 0.f};
#pragma unroll
    for (int jf = 0; jf < 11; ++jf)
#pragma unroll
        for (int r = 0; r < 4; ++r) {
            float e = __expf(acS[jf][r] - mx[r]);
            acS[jf][r] = e;
            sm[r] += e;
        }
#pragma unroll
    for (int r = 0; r < 4; ++r) {
#pragma unroll
        for (int off = 8; off; off >>= 1) sm[r] += __shfl_xor(sm[r], off);
        sm[r] = 1.f / sm[r];
    }
    __syncthreads();

    s16x8 vr0 = *vsrc(12 + w * 3 + 0);
    s16x8 vr1 = *vsrc(12 + w * 3 + 1);
    s16x8 vr2 = *vsrc(12 + w * 3 + 2);

#pragma unroll
    for (int jf = 0; jf < 11; ++jf)
#pragma unroll
        for (int r = 0; r < 4; ++r)
            Pl[(m0 + (lane >> 4) * 4 + r) * 200 + jf * 16 + lr] = f2bf(acS[jf][r]);
#pragma unroll
    for (int r = 0; r < 4; ++r)
        Pl[(m0 + (lane >> 4) * 4 + r) * 200 + 176 + lr] = 0;

    s16x8 pa[6];
#pragma unroll
    for (int ks = 0; ks < 6; ++ks)
        pa[ks] = *(const s16x8*)&Pl[(m0 + lr) * 200 + ks * 32 + lk];

    const unsigned vbase = LDSOFF(Vsub);
#pragma unroll
    for (int nf = 0; nf < 2; ++nf) {
        const unsigned abase = vbase + (nf & 1) * 6144 + ((lane >> 4) << 8) + ((lane & 15) << 1);
        s16x4 lo[6], hi[6];
#pragma unroll
        for (int ks = 0; ks < 6; ++ks) {
            lo[ks] = tr_read(abase + ks * 1024);
            hi[ks] = tr_read128(abase + ks * 1024);
        }
        asm volatile("s_waitcnt lgkmcnt(0)" ::: "memory");
        __builtin_amdgcn_sched_barrier(0);
        f32x4 acO = {};
        __builtin_amdgcn_s_setprio(1);
#pragma unroll
        for (int ks = 0; ks < 6; ++ks) {
            s16x8 vb = __builtin_shufflevector(lo[ks], hi[ks], 0, 1, 2, 3, 4, 5, 6, 7);
            acO = __builtin_amdgcn_mfma_f32_16x16x32_bf16(pa[ks], vb, acO, 0, 0, 0);
        }
        __builtin_amdgcn_s_setprio(0);
#pragma unroll
        for (int r = 0; r < 4; ++r) {
            const int t = t0 + m0 + (lane >> 4) * 4 + r;
            if (t < TSEQ)
                o[(size_t)(b * TSEQ + t) * CDIM + h * DKK + nf * 16 + lr] =
                    f2bf(acO[r] * sm[r]);
        }
    }
    __syncthreads();

    *(s16x8*)((char*)Vsub + (w * 3 + 0) * 1024 + lane * 16) = vr0;
    *(s16x8*)((char*)Vsub + (w * 3 + 1) * 1024 + lane * 16) = vr1;
    *(s16x8*)((char*)Vsub + (w * 3 + 2) * 1024 + lane * 16) = vr2;
    __syncthreads();

#pragma unroll
    for (int nf = 2; nf < 4; ++nf) {
        const unsigned abase = vbase + (nf & 1) * 6144 + ((lane >> 4) << 8) + ((lane & 15) << 1);
        s16x4 lo[6], hi[6];
#pragma unroll
        for (int ks = 0; ks < 6; ++ks) {
            lo[ks] = tr_read(abase + ks * 1024);
            hi[ks] = tr_read128(abase + ks * 1024);
        }
        asm volatile("s_waitcnt lgkmcnt(0)" ::: "memory");
        __builtin_amdgcn_sched_barrier(0);
        f32x4 acO = {};
        __builtin_amdgcn_s_setprio(1);
#pragma unroll
        for (int ks = 0; ks < 6; ++ks) {
            s16x8 vb = __builtin_shufflevector(lo[ks], hi[ks], 0, 1, 2, 3, 4, 5, 6, 7);
            acO = __builtin_amdgcn_mfma_f32_16x16x32_bf16(pa[ks], vb, acO, 0, 0, 0);
        }
        __builtin_amdgcn_s_setprio(0);
#pragma unroll
        for (int r = 0; r < 4; ++r) {
            const int t = t0 + m0 + (lane >> 4) * 4 + r;
            if (t < TSEQ)
                o[(size_t)(b * TSEQ + t) * CDIM + h * DKK + nf * 16 + lr] =
                    f2bf(acO[r] * sm[r]);
        }
    }
}

// ---------------- launch ----------------
extern "C" void kernel_launch(void* const* d_in, const int* in_sizes, int n_in,
                              void* d_out, int out_size, void* d_ws, size_t ws_size,
                              hipStream_t stream) {
    const float* x     = (const float*)d_in[0];
    const float* Wq    = (const float*)d_in[1];
    const float* bq    = (const float*)d_in[2];
    const float* Wk    = (const float*)d_in[3];
    const float* bk    = (const float*)d_in[4];
    const float* Wv    = (const float*)d_in[5];
    const float* bv    = (const float*)d_in[6];
    const float* Wo    = (const float*)d_in[7];
    const float* bo    = (const float*)d_in[8];
    const float* Wp    = (const float*)d_in[9];
    const float* pos_u = (const float*)d_in[10];
    const float* pos_v = (const float*)d_in[11];
    const float* ln1g  = (const float*)d_in[12];
    const float* ln1b  = (const float*)d_in[13];
    const float* ln2g  = (const float*)d_in[14];
    const float* ln2b  = (const float*)d_in[15];
    const float* W1    = (const float*)d_in[16];
    const float* b1    = (const float*)d_in[17];
    const float* W2    = (const float*)d_in[18];
    const float* b2    = (const float*)d_in[19];

    float* h = (float*)d_out;
    const float XS = 27.712812921102035f;   // sqrt(768)

    char* p = (char*)d_ws;
    ushort* Wtqkv = (ushort*)p;               p += (size_t)LNUM * QKVDIM * CDIM * 2;
    ushort* Wtp   = (ushort*)p;               p += (size_t)LNUM * CDIM * CDIM * 2;
    ushort* Wto   = (ushort*)p;               p += (size_t)LNUM * CDIM * CDIM * 2;
    ushort* Wt1   = (ushort*)p;               p += (size_t)LNUM * CDIM * CDIM * 2;
    ushort* Wt2   = (ushort*)p;               p += (size_t)LNUM * CDIM * CDIM * 2;
    float*  bqkv  = (float*)p;                p += (size_t)LNUM * QKVDIM * 4;
    ushort* pe    = (ushort*)p;               p += (size_t)2048 * CDIM * 2;
    ushort* pb    = (ushort*)p;               p += (size_t)LNUM * 2048 * CDIM * 2;
    ushort* y     = (ushort*)p;               p += (size_t)MPAD * CDIM * 2;
    ushort* qkv   = (ushort*)p;               p += (size_t)MPAD * QKVDIM * 2;
    ushort* o     = (ushort*)p;               p += (size_t)MPAD * CDIM * 2;
    ushort* hid   = (ushort*)p;               p += (size_t)MPAD * CDIM * 2;

    transpose_pack<<<dim3(24, 24, 15), dim3(8, 32), 0, stream>>>(
        Wq, Wk, Wv, Wp, Wo, W1, W2, Wtqkv, Wtp, Wto, Wt1, Wt2,
        pe, bq, bk, bv, bqkv);

    const int MB = (MROWS + 63) / 64;        // 63 row-blocks
    const dim3 gQKV(32, QKVDIM / 128);       // 128x128 tiles: (32, 18) = 576 blocks
    const dim3 gC(MB, CDIM / 64);            // 64x64 tiles: (63, 12) = 756 blocks
    const dim3 gP(4, CDIM / 64, LNUM);       // (4, 12, 2)
    const dim3 gA(16, HHEADS, BBATCH);

    gemm64x64<0><<<gP, 256, 0, stream>>>(pe + (size_t)896 * CDIM, Wtp, nullptr,
                                         pb + (size_t)896 * CDIM, 256, CDIM,
                                         nullptr, 0.f,
                                         (size_t)CDIM * CDIM, (size_t)2048 * CDIM);

    for (int l = 0; l < LNUM; ++l) {
        const size_t wo = (size_t)l * CDIM * CDIM;
        const float* res1 = (l == 0) ? x : h;
        const float rs1   = (l == 0) ? XS : 1.f;
        ln_kernel<<<MROWS / 4, 256, 0, stream>>>(res1, ln1g + l * CDIM, ln1b + l * CDIM, y, rs1);
        gemm128<0><<<gQKV, 256, 0, stream>>>(y, Wtqkv + (size_t)l * QKVDIM * CDIM,
                                             bqkv + l * QKVDIM, qkv, MROWS, QKVDIM);
        attn_mfma<<<gA, 256, 0, stream>>>(
            qkv, pb + (size_t)l * 2048 * CDIM,
            pos_u + l * HHEADS * DKK, pos_v + l * HHEADS * DKK, o);
        gemm64x64<2><<<gC, 256, 0, stream>>>(o, Wto + wo, bo + l * CDIM, h, MROWS, CDIM,
                                             res1, rs1, 0, 0);
        ln_kernel<<<MROWS / 4, 256, 0, stream>>>(h, ln2g + l * CDIM, ln2b + l * CDIM, y, 1.f);
        gemm64x64<1><<<gC, 256, 0, stream>>>(y, Wt1 + wo, b1 + l * CDIM, hid, MROWS, CDIM,
                                             nullptr, 0.f, 0, 0);
        gemm64x64<2><<<gC, 256, 0, stream>>>(hid, Wt2 + wo, b2 + l * CDIM, h, MROWS, CDIM,
                                             h, 1.f, 0, 0);
    }
}